// Round 1
// baseline (1258.798 us; speedup 1.0000x reference)
//
#include <hip/hip_runtime.h>
#include <hip/hip_bf16.h>
#include <math.h>

typedef __hip_bfloat16 bf16;

#define NNODES 2000
#define NEDGE_IN 16000
#define NEDGE 18000
#define NGRAPH 40

__device__ __forceinline__ float bf2f(bf16 v){ return __bfloat162float(v); }
__device__ __forceinline__ bf16 f2bf(float v){ return __float2bfloat16(v); }

// ---------- setup kernels ----------
__global__ void k_mean_ea(const float* __restrict__ ea, float* __restrict__ mean_ea){
  __shared__ float s0l[256], s1l[256];
  float s0=0.f, s1=0.f;
  for (int e = threadIdx.x; e < NEDGE_IN; e += 256){ s0 += ea[2*e]; s1 += ea[2*e+1]; }
  s0l[threadIdx.x]=s0; s1l[threadIdx.x]=s1; __syncthreads();
  for (int d=128; d>=1; d>>=1){
    if ((int)threadIdx.x < d){ s0l[threadIdx.x]+=s0l[threadIdx.x+d]; s1l[threadIdx.x]+=s1l[threadIdx.x+d]; }
    __syncthreads();
  }
  if (threadIdx.x==0){ mean_ea[0]=s0l[0]/(float)NEDGE_IN; mean_ea[1]=s1l[0]/(float)NEDGE_IN; }
}

__global__ void k_count(const int* __restrict__ ei, int* __restrict__ cnt){
  int e = blockIdx.x*256 + threadIdx.x;
  if (e >= NEDGE) return;
  int d = (e < NEDGE_IN) ? ei[NEDGE_IN + e] : (e - NEDGE_IN);
  atomicAdd(&cnt[d], 1);
}

__global__ void k_scan(const int* __restrict__ cnt, int* __restrict__ off){
  __shared__ int s[2048];
  int lane = threadIdx.x; // 64 threads
  for (int i = lane; i < 2048; i += 64) s[i] = (i < NNODES) ? cnt[i] : 0;
  __syncthreads();
  int base = lane*32, run = 0;
  for (int j=0;j<32;j++){ int t = s[base+j]; s[base+j] = run; run += t; }
  int x = run;
  for (int d=1; d<64; d<<=1){ int y = __shfl_up(x, d); if (lane >= d) x += y; }
  int chunkOff = x - run; // exclusive prefix of chunk sums
  for (int j=0;j<32;j++){ int idx = base+j; if (idx <= NNODES) off[idx] = chunkOff + s[idx]; }
}

__global__ void k_scatter(const int* __restrict__ ei, const int* __restrict__ off,
                          int* __restrict__ cursor, int* __restrict__ csr_src, int* __restrict__ epos){
  int e = blockIdx.x*256 + threadIdx.x;
  if (e >= NEDGE) return;
  int d, sn;
  if (e < NEDGE_IN){ sn = ei[e]; d = ei[NEDGE_IN+e]; } else { sn = e-NEDGE_IN; d = sn; }
  int p = off[d] + atomicAdd(&cursor[d], 1);
  csr_src[p] = sn;
  epos[e] = p;
}

__global__ void k_whht(const float* __restrict__ whh, float* __restrict__ whhT){
  int idx = blockIdx.x*256 + threadIdx.x;
  if (idx >= 1024*256) return;
  int j = idx >> 8, k = idx & 255;
  whhT[k*1024 + j] = whh[idx];
}

// ---------- edge-feature projection (into CSR-permuted order, bf16) ----------
template<int HC>
__global__ void k_ee(const float* __restrict__ ea, const float* __restrict__ mean_ea,
                     const float* __restrict__ We, const int* __restrict__ epos,
                     bf16* __restrict__ eeP){
  int idx = blockIdx.x*256 + threadIdx.x;
  if (idx >= NEDGE*HC) return;
  int e = idx / HC, hc = idx % HC;
  float a0, a1;
  if (e < NEDGE_IN){ a0 = ea[2*e]; a1 = ea[2*e+1]; } else { a0 = mean_ea[0]; a1 = mean_ea[1]; }
  float v = a0*We[hc] + a1*We[HC+hc];
  eeP[(size_t)epos[e]*HC + hc] = f2bf(v);
}

// ---------- batched node-feature GEMM: Y[80000,N] = X[80000,K] @ W[K,N] ----------
template<int K, int N>
__global__ __launch_bounds__(256) void k_gemm(const float* __restrict__ X, const float* __restrict__ W,
                                              bf16* __restrict__ Y){
  __shared__ float Ws[K*N];
  for (int i = threadIdx.x; i < K*N; i += 256) Ws[i] = W[i];
  __syncthreads();
  const int RG = 256/N;       // row groups per block
  const int RB = RG*4;        // rows per block (each thread 4 rows)
  int j  = threadIdx.x % N;
  int rg = threadIdx.x / N;
  size_t m0 = (size_t)blockIdx.x*RB + (size_t)rg*4;
  const float* x0 = X + m0*K;
  float a0=0.f,a1=0.f,a2=0.f,a3=0.f;
  #pragma unroll 8
  for (int k=0;k<K;k++){
    float w = Ws[k*N + j];
    a0 += x0[k]*w; a1 += x0[K+k]*w; a2 += x0[2*K+k]*w; a3 += x0[3*K+k]*w;
  }
  bf16* y = Y + m0*N + j;
  y[0] = f2bf(a0); y[N] = f2bf(a1); y[2*N] = f2bf(a2); y[3*N] = f2bf(a3);
}

// ---------- GATv2 edge + online-softmax + aggregate + bias + relu ----------
template<int H, int C>
__global__ __launch_bounds__(128) void k_edge(const bf16* __restrict__ XL, const bf16* __restrict__ XR,
                                              const bf16* __restrict__ eeP, const int* __restrict__ off,
                                              const int* __restrict__ csr_src, const float* __restrict__ att,
                                              const float* __restrict__ bias, float* __restrict__ Hout){
  const int HC = H*C;
  const int NPB = 128/HC;
  int hc = threadIdx.x % HC;
  int n  = blockIdx.x*NPB + threadIdx.x/HC;
  int g  = blockIdx.y;
  size_t gbase = (size_t)g*NNODES*HC;
  float xr = bf2f(XR[gbase + (size_t)n*HC + hc]);
  float av = att[hc];
  float mrun = -INFINITY, srun = 0.f, acc = 0.f;
  int p0 = off[n], p1 = off[n+1];
  for (int p = p0; p < p1; ++p){
    int u = csr_src[p];
    float xl = bf2f(XL[gbase + (size_t)u*HC + hc]);
    float sum = xl + xr + bf2f(eeP[(size_t)p*HC + hc]);
    float m = sum > 0.f ? sum : 0.2f*sum;
    float contrib = m*av;
    #pragma unroll
    for (int d=C/2; d>=1; d>>=1) contrib += __shfl_xor(contrib, d);
    float logit = contrib;
    if (logit > mrun){
      float sc = __expf(mrun - logit);
      srun *= sc; acc *= sc; mrun = logit;
    }
    float pe = __expf(logit - mrun);
    srun += pe; acc += pe*xl;
  }
  float o = acc/(srun + 1e-16f) + bias[hc];
  Hout[gbase + (size_t)n*HC + hc] = o > 0.f ? o : 0.f;
}

// ---------- gates_x[bt][j] = emb[bt] . w_ih[j]  (k-split, register-blocked) ----------
__global__ __launch_bounds__(256) void k_gates(const float* __restrict__ emb, const float* __restrict__ w_ih,
                                               float* __restrict__ gates){
  __shared__ float se[NGRAPH][256]; // 40 KB
  int tid = threadIdx.x;
  int s = tid & 7, jg = (tid >> 3) & 7, btg = tid >> 6;
  int jbase = blockIdx.x*64 + jg*8;
  int bt0 = btg*10;
  float acc[8][10];
  #pragma unroll
  for (int a=0;a<8;a++)
    #pragma unroll
    for (int b=0;b<10;b++) acc[a][b]=0.f;
  for (int cchunk=0; cchunk<10; ++cchunk){
    int k0 = blockIdx.y*2560 + cchunk*256;
    __syncthreads();
    for (int i = tid; i < NGRAPH*256; i += 256){
      int bt = i >> 8, kk = i & 255;
      se[bt][kk] = emb[(size_t)bt*64000 + k0 + kk];
    }
    __syncthreads();
    for (int i=0;i<32;i++){
      int kk = s + 8*i;
      float w[8];
      #pragma unroll
      for (int jr=0;jr<8;jr++) w[jr] = w_ih[(size_t)(jbase+jr)*64000 + k0 + kk];
      #pragma unroll
      for (int b=0;b<10;b++){
        float e = se[bt0+b][kk];
        #pragma unroll
        for (int jr=0;jr<8;jr++) acc[jr][b] += w[jr]*e;
      }
    }
  }
  #pragma unroll
  for (int jr=0;jr<8;jr++)
    #pragma unroll
    for (int b=0;b<10;b++){
      float v = acc[jr][b];
      v += __shfl_xor(v,1); v += __shfl_xor(v,2); v += __shfl_xor(v,4);
      if (s==0) atomicAdd(&gates[(size_t)(bt0+b)*1024 + jbase+jr], v);
    }
}

// ---------- one LSTM time step: 4 blocks (one per batch), 1024 threads ----------
__global__ __launch_bounds__(1024) void k_lstm(const float* __restrict__ gates, const float* __restrict__ whhT,
                                               const float* __restrict__ b_ih, const float* __restrict__ b_hh,
                                               float* __restrict__ hst, float* __restrict__ cst, int t){
  __shared__ float g[1024];
  int b = blockIdx.x, j = threadIdx.x;
  const float* h = hst + b*256;
  float a0=0.f,a1=0.f,a2=0.f,a3=0.f;
  for (int k=0;k<256;k+=4){
    a0 += h[k]   * whhT[(k  )*1024 + j];
    a1 += h[k+1] * whhT[(k+1)*1024 + j];
    a2 += h[k+2] * whhT[(k+2)*1024 + j];
    a3 += h[k+3] * whhT[(k+3)*1024 + j];
  }
  float acc = gates[(size_t)(b*10 + t)*1024 + j] + b_ih[j] + b_hh[j] + a0+a1+a2+a3;
  g[j] = acc;
  __syncthreads();
  if (j < 256){
    float i_ = g[j], f_ = g[j+256], gg = g[j+512], o_ = g[j+768];
    float si = 1.f/(1.f+__expf(-i_));
    float sf = 1.f/(1.f+__expf(-f_));
    float so = 1.f/(1.f+__expf(-o_));
    float c = sf*cst[b*256+j] + si*tanhf(gg);
    float hn = so*tanhf(c);
    cst[b*256+j] = c; hst[b*256+j] = hn;
  }
}

// ---------- head: relu(h) @ fc1 -> relu -> @ fc2 ----------
__global__ __launch_bounds__(512) void k_head(const float* __restrict__ hst, const float* __restrict__ fc1w,
                                              const float* __restrict__ fc1b, const float* __restrict__ fc2w,
                                              const float* __restrict__ fc2b, float* __restrict__ out){
  __shared__ float r[512];
  int b = blockIdx.x, j = threadIdx.x;
  float acc = fc1b[j];
  for (int k=0;k<256;k++){
    float l = hst[b*256+k]; l = l>0.f?l:0.f;
    acc += l * fc1w[k*512 + j];
  }
  float hid = acc>0.f?acc:0.f;
  r[j] = hid * fc2w[j];
  __syncthreads();
  for (int d=256; d>=1; d>>=1){ if (j<d) r[j]+=r[j+d]; __syncthreads(); }
  if (j==0) out[b] = r[0] + fc2b[0];
}

extern "C" void kernel_launch(void* const* d_in, const int* in_sizes, int n_in,
                              void* d_out, int out_size, void* d_ws, size_t ws_size,
                              hipStream_t stream){
  const float* x    = (const float*)d_in[0];
  const int*   ei   = (const int*)  d_in[1];
  const float* ea   = (const float*)d_in[2];
  const float* wl0  = (const float*)d_in[3];
  const float* wr0  = (const float*)d_in[4];
  const float* we0  = (const float*)d_in[5];
  const float* att0 = (const float*)d_in[6];
  const float* b0   = (const float*)d_in[7];
  const float* wl1  = (const float*)d_in[8];
  const float* wr1  = (const float*)d_in[9];
  const float* we1  = (const float*)d_in[10];
  const float* att1 = (const float*)d_in[11];
  const float* b1   = (const float*)d_in[12];
  const float* wl2  = (const float*)d_in[13];
  const float* wr2  = (const float*)d_in[14];
  const float* we2  = (const float*)d_in[15];
  const float* att2 = (const float*)d_in[16];
  const float* b2   = (const float*)d_in[17];
  const float* wih  = (const float*)d_in[18];
  const float* whh  = (const float*)d_in[19];
  const float* bih  = (const float*)d_in[20];
  const float* bhh  = (const float*)d_in[21];
  const float* fc1w = (const float*)d_in[22];
  const float* fc1b = (const float*)d_in[23];
  const float* fc2w = (const float*)d_in[24];
  const float* fc2b = (const float*)d_in[25];
  float* out = (float*)d_out;

  char* base = (char*)d_ws; size_t cur = 0;
  auto alloc = [&](size_t bytes)->void*{
    cur = (cur + 255) & ~(size_t)255; void* p = base + cur; cur += bytes; return p;
  };
  float* mean_ea = (float*)alloc(8);
  int*   cnt     = (int*)  alloc((size_t)NNODES*4);
  int*   off     = (int*)  alloc((size_t)(NNODES+1)*4);
  int*   cursor  = (int*)  alloc((size_t)NNODES*4);
  int*   csr_src = (int*)  alloc((size_t)NEDGE*4);
  int*   epos    = (int*)  alloc((size_t)NEDGE*4);
  bf16*  eeP     = (bf16*) alloc((size_t)NEDGE*128*2);
  bf16*  XL      = (bf16*) alloc((size_t)80000*128*2);
  bf16*  XR      = (bf16*) alloc((size_t)80000*128*2);
  float* HBUF    = (float*)alloc((size_t)80000*128*4);
  float* gates   = (float*)alloc((size_t)40*1024*4);
  float* hst     = (float*)alloc(4*256*4);
  float* cst     = (float*)alloc(4*256*4);
  float* whhT    = (float*)alloc((size_t)256*1024*4);

  hipMemsetAsync(cnt,    0, (size_t)NNODES*4, stream);
  hipMemsetAsync(cursor, 0, (size_t)NNODES*4, stream);
  hipMemsetAsync(gates,  0, (size_t)40*1024*4, stream);
  hipMemsetAsync(hst,    0, 4*256*4, stream);
  hipMemsetAsync(cst,    0, 4*256*4, stream);

  k_mean_ea<<<1,256,0,stream>>>(ea, mean_ea);
  k_count  <<<(NEDGE+255)/256,256,0,stream>>>(ei, cnt);
  k_scan   <<<1,64,0,stream>>>(cnt, off);
  k_scatter<<<(NEDGE+255)/256,256,0,stream>>>(ei, off, cursor, csr_src, epos);
  k_whht   <<<1024,256,0,stream>>>(whh, whhT);

  // Layer 0 (Fin=8 -> H=4,C=32)
  k_ee<128> <<<(NEDGE*128)/256,256,0,stream>>>(ea, mean_ea, we0, epos, eeP);
  k_gemm<8,128> <<<10000,256,0,stream>>>(x, wl0, XL);
  k_gemm<8,128> <<<10000,256,0,stream>>>(x, wr0, XR);
  k_edge<4,32> <<<dim3(2000,40),128,0,stream>>>(XL,XR,eeP,off,csr_src,att0,b0,HBUF);

  // Layer 1 (128 -> H=4,C=32)
  k_ee<128> <<<(NEDGE*128)/256,256,0,stream>>>(ea, mean_ea, we1, epos, eeP);
  k_gemm<128,128> <<<10000,256,0,stream>>>(HBUF, wl1, XL);
  k_gemm<128,128> <<<10000,256,0,stream>>>(HBUF, wr1, XR);
  k_edge<4,32> <<<dim3(2000,40),128,0,stream>>>(XL,XR,eeP,off,csr_src,att1,b1,HBUF);

  // Layer 2 (128 -> H=4,C=8), output = emb [80000 x 32] in HBUF
  k_ee<32> <<<(NEDGE*32)/256,256,0,stream>>>(ea, mean_ea, we2, epos, eeP);
  k_gemm<128,32> <<<2500,256,0,stream>>>(HBUF, wl2, XL);
  k_gemm<128,32> <<<2500,256,0,stream>>>(HBUF, wr2, XR);
  k_edge<4,8> <<<dim3(500,40),128,0,stream>>>(XL,XR,eeP,off,csr_src,att2,b2,HBUF);

  // emb @ w_ih^T
  k_gates<<<dim3(16,25),256,0,stream>>>(HBUF, wih, gates);

  // LSTM recurrence
  for (int t=0;t<10;t++)
    k_lstm<<<4,1024,0,stream>>>(gates, whhT, bih, bhh, hst, cst, t);

  k_head<<<4,512,0,stream>>>(hst, fc1w, fc1b, fc2w, fc2b, out);
}

// Round 2
// 813.589 us; speedup vs baseline: 1.5472x; 1.5472x over previous
//
#include <hip/hip_runtime.h>
#include <hip/hip_bf16.h>
#include <math.h>

typedef __hip_bfloat16 bf16;
typedef __attribute__((ext_vector_type(8))) short short8;
typedef __attribute__((ext_vector_type(4))) float f32x4;

#define NNODES 2000
#define NEDGE_IN 16000
#define NEDGE 18000
#define NGRAPH 40

__device__ __forceinline__ float bf2f(bf16 v){ return __bfloat162float(v); }
__device__ __forceinline__ bf16 f2bf(float v){ return __float2bfloat16(v); }

// ---------- setup kernels ----------
__global__ void k_mean_ea(const float* __restrict__ ea, float* __restrict__ mean_ea){
  __shared__ float s0l[256], s1l[256];
  float s0=0.f, s1=0.f;
  for (int e = threadIdx.x; e < NEDGE_IN; e += 256){ s0 += ea[2*e]; s1 += ea[2*e+1]; }
  s0l[threadIdx.x]=s0; s1l[threadIdx.x]=s1; __syncthreads();
  for (int d=128; d>=1; d>>=1){
    if ((int)threadIdx.x < d){ s0l[threadIdx.x]+=s0l[threadIdx.x+d]; s1l[threadIdx.x]+=s1l[threadIdx.x+d]; }
    __syncthreads();
  }
  if (threadIdx.x==0){ mean_ea[0]=s0l[0]/(float)NEDGE_IN; mean_ea[1]=s1l[0]/(float)NEDGE_IN; }
}

__global__ void k_count(const int* __restrict__ ei, int* __restrict__ cnt){
  int e = blockIdx.x*256 + threadIdx.x;
  if (e >= NEDGE) return;
  int d = (e < NEDGE_IN) ? ei[NEDGE_IN + e] : (e - NEDGE_IN);
  atomicAdd(&cnt[d], 1);
}

__global__ void k_scan(const int* __restrict__ cnt, int* __restrict__ off){
  __shared__ int s[2048];
  int lane = threadIdx.x; // 64 threads
  for (int i = lane; i < 2048; i += 64) s[i] = (i < NNODES) ? cnt[i] : 0;
  __syncthreads();
  int base = lane*32, run = 0;
  for (int j=0;j<32;j++){ int t = s[base+j]; s[base+j] = run; run += t; }
  int x = run;
  for (int d=1; d<64; d<<=1){ int y = __shfl_up(x, d); if (lane >= d) x += y; }
  int chunkOff = x - run;
  for (int j=0;j<32;j++){ int idx = base+j; if (idx <= NNODES) off[idx] = chunkOff + s[idx]; }
}

__global__ void k_scatter(const int* __restrict__ ei, const int* __restrict__ off,
                          int* __restrict__ cursor, int* __restrict__ csr_src, int* __restrict__ epos){
  int e = blockIdx.x*256 + threadIdx.x;
  if (e >= NEDGE) return;
  int d, sn;
  if (e < NEDGE_IN){ sn = ei[e]; d = ei[NEDGE_IN+e]; } else { sn = e-NEDGE_IN; d = sn; }
  int p = off[d] + atomicAdd(&cursor[d], 1);
  csr_src[p] = sn;
  epos[e] = p;
}

// pack whh[j][k] -> whhT2[k/2][j] as (bf16(k+1)<<16)|bf16(k)
__global__ void k_prep_whh(const float* __restrict__ whh, unsigned* __restrict__ whhT2){
  int idx = blockIdx.x*256 + threadIdx.x;
  if (idx >= 1024*128) return;
  int j = idx >> 7, kp = idx & 127;
  bf16 lo = f2bf(whh[j*256 + 2*kp]);
  bf16 hi = f2bf(whh[j*256 + 2*kp + 1]);
  unsigned ulo = *(unsigned short*)&lo;
  unsigned uhi = *(unsigned short*)&hi;
  whhT2[kp*1024 + j] = (uhi<<16) | ulo;
}

// convert the 4 layer-1/2 weight matrices W[k][n] (f32) -> BT[n][k] (bf16, row len 128)
__global__ void k_wcvt(const float* __restrict__ w1a, const float* __restrict__ w1b,
                       const float* __restrict__ w2a, const float* __restrict__ w2b,
                       bf16* __restrict__ b1a, bf16* __restrict__ b1b,
                       bf16* __restrict__ b2a, bf16* __restrict__ b2b){
  int idx = blockIdx.x*256 + threadIdx.x; // 40960 total
  if (idx >= 40960) return;
  const float* src; bf16* dst; int n, local;
  if (idx < 16384){ src=w1a; dst=b1a; n=128; local=idx; }
  else if (idx < 32768){ src=w1b; dst=b1b; n=128; local=idx-16384; }
  else if (idx < 36864){ src=w2a; dst=b2a; n=32; local=idx-32768; }
  else { src=w2b; dst=b2b; n=32; local=idx-36864; }
  int k = local / n, c = local % n;
  dst[c*128 + k] = f2bf(src[local]);
}

// ---------- edge-feature projection (into CSR-permuted order, bf16) ----------
template<int HC>
__global__ void k_ee(const float* __restrict__ ea, const float* __restrict__ mean_ea,
                     const float* __restrict__ We, const int* __restrict__ epos,
                     bf16* __restrict__ eeP){
  int idx = blockIdx.x*256 + threadIdx.x;
  if (idx >= NEDGE*HC) return;
  int e = idx / HC, hc = idx % HC;
  float a0, a1;
  if (e < NEDGE_IN){ a0 = ea[2*e]; a1 = ea[2*e+1]; } else { a0 = mean_ea[0]; a1 = mean_ea[1]; }
  float v = a0*We[hc] + a1*We[HC+hc];
  eeP[(size_t)epos[e]*HC + hc] = f2bf(v);
}

// ---------- layer-0 GEMM (K=8, fp32 input): Y[80000,128] = X @ W ----------
template<int K, int N>
__global__ __launch_bounds__(256) void k_gemm(const float* __restrict__ X, const float* __restrict__ W,
                                              bf16* __restrict__ Y){
  __shared__ float Ws[K*N];
  for (int i = threadIdx.x; i < K*N; i += 256) Ws[i] = W[i];
  __syncthreads();
  const int RG = 256/N;
  const int RB = RG*4;
  int j  = threadIdx.x % N;
  int rg = threadIdx.x / N;
  size_t m0 = (size_t)blockIdx.x*RB + (size_t)rg*4;
  const float* x0 = X + m0*K;
  float a0=0.f,a1=0.f,a2=0.f,a3=0.f;
  #pragma unroll
  for (int k=0;k<K;k++){
    float w = Ws[k*N + j];
    a0 += x0[k]*w; a1 += x0[K+k]*w; a2 += x0[2*K+k]*w; a3 += x0[3*K+k]*w;
  }
  bf16* y = Y + m0*N + j;
  y[0] = f2bf(a0); y[N] = f2bf(a1); y[2*N] = f2bf(a2); y[3*N] = f2bf(a3);
}

// ---------- MFMA GEMM: Y[M,N](bf16) = A[M,128](bf16) @ B (BT[n][128] bf16) ----------
template<int N>
__global__ __launch_bounds__(256,4) void k_gemm_mf(const bf16* __restrict__ A, const bf16* __restrict__ BT,
                                                   bf16* __restrict__ Y){
  const int NT = N/16;
  int lane = threadIdx.x & 63, wv = threadIdx.x >> 6;
  size_t m0 = (size_t)blockIdx.x*128 + (size_t)wv*32;
  int r = lane & 15, kg = lane >> 4;
  const f32x4 zero = {0.f,0.f,0.f,0.f};
  f32x4 acc[2][NT];
  #pragma unroll
  for (int s=0;s<2;s++)
    #pragma unroll
    for (int t=0;t<NT;t++) acc[s][t] = zero;
  #pragma unroll
  for (int c=0;c<4;c++){
    short8 a0 = *(const short8*)(A + (m0 + r)*128 + c*32 + kg*8);
    short8 a1 = *(const short8*)(A + (m0 + 16 + r)*128 + c*32 + kg*8);
    #pragma unroll
    for (int t=0;t<NT;t++){
      short8 bfr = *(const short8*)(BT + (size_t)(t*16 + r)*128 + c*32 + kg*8);
      acc[0][t] = __builtin_amdgcn_mfma_f32_16x16x32_bf16(a0, bfr, acc[0][t], 0,0,0);
      acc[1][t] = __builtin_amdgcn_mfma_f32_16x16x32_bf16(a1, bfr, acc[1][t], 0,0,0);
    }
  }
  #pragma unroll
  for (int s=0;s<2;s++)
    #pragma unroll
    for (int t=0;t<NT;t++){
      size_t row = m0 + s*16 + kg*4;
      int col = t*16 + r;
      #pragma unroll
      for (int i=0;i<4;i++)
        Y[(row+i)*N + col] = f2bf(acc[s][t][i]);
    }
}

// ---------- GATv2 edge + online-softmax + aggregate + bias + relu (bf16 out) ----------
template<int H, int C>
__global__ __launch_bounds__(128) void k_edge(const bf16* __restrict__ XL, const bf16* __restrict__ XR,
                                              const bf16* __restrict__ eeP, const int* __restrict__ off,
                                              const int* __restrict__ csr_src, const float* __restrict__ att,
                                              const float* __restrict__ bias, bf16* __restrict__ Hout){
  const int HC = H*C;
  const int NPB = 128/HC;
  int hc = threadIdx.x % HC;
  int n  = blockIdx.x*NPB + threadIdx.x/HC;
  int g  = blockIdx.y;
  size_t gbase = (size_t)g*NNODES*HC;
  float xr = bf2f(XR[gbase + (size_t)n*HC + hc]);
  float av = att[hc];
  float mrun = -INFINITY, srun = 0.f, acc = 0.f;
  int p0 = off[n], p1 = off[n+1];
  for (int p = p0; p < p1; ++p){
    int u = csr_src[p];
    float xl = bf2f(XL[gbase + (size_t)u*HC + hc]);
    float sum = xl + xr + bf2f(eeP[(size_t)p*HC + hc]);
    float m = sum > 0.f ? sum : 0.2f*sum;
    float contrib = m*av;
    #pragma unroll
    for (int d=C/2; d>=1; d>>=1) contrib += __shfl_xor(contrib, d);
    float logit = contrib;
    if (logit > mrun){
      float sc = __expf(mrun - logit);
      srun *= sc; acc *= sc; mrun = logit;
    }
    float pe = __expf(logit - mrun);
    srun += pe; acc += pe*xl;
  }
  float o = acc/(srun + 1e-16f) + bias[hc];
  Hout[gbase + (size_t)n*HC + hc] = f2bf(o > 0.f ? o : 0.f);
}

// ---------- gates_x[bt][j] = emb[bt] . w_ih[j]  (LDS-free streaming, k-split) ----------
__global__ __launch_bounds__(256,3) void k_gates2(const bf16* __restrict__ emb, const float* __restrict__ wih,
                                                  float* __restrict__ gates){
  int lane = threadIdx.x & 63, wv = threadIdx.x >> 6;
  int jbase = blockIdx.x * 8;            // 128 j-groups
  int b0 = wv * 10;                      // 4 waves x 10 bt
  size_t kbase = (size_t)blockIdx.y * 12800;  // 5 k-splits, 50 chunks of 256
  float acc[8][10];
  #pragma unroll
  for (int jj=0;jj<8;jj++)
    #pragma unroll
    for (int b=0;b<10;b++) acc[jj][b] = 0.f;
  const float* wp0 = wih + (size_t)jbase*64000 + kbase + (size_t)lane*4;
  const bf16*  ep0 = emb + (size_t)b0*64000 + kbase + (size_t)lane*4;
  for (int ch=0; ch<50; ++ch){
    size_t koff = (size_t)ch*256;
    float4 w4[8];
    #pragma unroll
    for (int jj=0;jj<8;jj++) w4[jj] = *(const float4*)(wp0 + (size_t)jj*64000 + koff);
    #pragma unroll
    for (int b=0;b<10;b++){
      uint2 u = *(const uint2*)(ep0 + (size_t)b*64000 + koff);
      float e0 = __uint_as_float(u.x << 16);
      float e1 = __uint_as_float(u.x & 0xffff0000u);
      float e2 = __uint_as_float(u.y << 16);
      float e3 = __uint_as_float(u.y & 0xffff0000u);
      #pragma unroll
      for (int jj=0;jj<8;jj++){
        float a = acc[jj][b];
        a = fmaf(w4[jj].x, e0, a);
        a = fmaf(w4[jj].y, e1, a);
        a = fmaf(w4[jj].z, e2, a);
        a = fmaf(w4[jj].w, e3, a);
        acc[jj][b] = a;
      }
    }
  }
  #pragma unroll
  for (int jj=0;jj<8;jj++)
    #pragma unroll
    for (int b=0;b<10;b++){
      float v = acc[jj][b];
      #pragma unroll
      for (int d=1; d<64; d<<=1) v += __shfl_xor(v, d);
      int id = jj*10 + b;
      if (lane == (id & 63))
        atomicAdd(&gates[(size_t)(b0+b)*1024 + jbase + jj], v);
    }
}

// ---------- fused 10-step LSTM: 4 blocks (one per batch) ----------
__global__ __launch_bounds__(1024) void k_lstm10(const float* __restrict__ gates, const unsigned* __restrict__ whhT2,
                                                 const float* __restrict__ bih, const float* __restrict__ bhh,
                                                 float* __restrict__ hst){
  __shared__ float hs[256];
  __shared__ float g[1024];
  int b = blockIdx.x, j = threadIdx.x;
  float c_reg = 0.f;
  if (j < 256) hs[j] = 0.f;
  float bias = bih[j] + bhh[j];
  __syncthreads();
  for (int t=0;t<10;t++){
    float acc = gates[(size_t)(b*10+t)*1024 + j] + bias;
    #pragma unroll 4
    for (int kp=0;kp<128;kp++){
      unsigned u = whhT2[kp*1024 + j];
      float2 h2 = *(const float2*)&hs[2*kp];
      acc = fmaf(__uint_as_float(u<<16), h2.x, acc);
      acc = fmaf(__uint_as_float(u & 0xffff0000u), h2.y, acc);
    }
    g[j] = acc;
    __syncthreads();
    if (j < 256){
      float i_ = g[j], f_ = g[j+256], gg = g[j+512], o_ = g[j+768];
      float si = 1.f/(1.f+__expf(-i_));
      float sf = 1.f/(1.f+__expf(-f_));
      float so = 1.f/(1.f+__expf(-o_));
      c_reg = sf*c_reg + si*tanhf(gg);
      float hn = so*tanhf(c_reg);
      hs[j] = hn;
      if (t==9) hst[b*256+j] = hn;
    }
    __syncthreads();
  }
}

// ---------- head: relu(h) @ fc1 -> relu -> @ fc2 ----------
__global__ __launch_bounds__(512) void k_head(const float* __restrict__ hst, const float* __restrict__ fc1w,
                                              const float* __restrict__ fc1b, const float* __restrict__ fc2w,
                                              const float* __restrict__ fc2b, float* __restrict__ out){
  __shared__ float r[512];
  int b = blockIdx.x, j = threadIdx.x;
  float acc = fc1b[j];
  for (int k=0;k<256;k++){
    float l = hst[b*256+k]; l = l>0.f?l:0.f;
    acc += l * fc1w[k*512 + j];
  }
  float hid = acc>0.f?acc:0.f;
  r[j] = hid * fc2w[j];
  __syncthreads();
  for (int d=256; d>=1; d>>=1){ if (j<d) r[j]+=r[j+d]; __syncthreads(); }
  if (j==0) out[b] = r[0] + fc2b[0];
}

extern "C" void kernel_launch(void* const* d_in, const int* in_sizes, int n_in,
                              void* d_out, int out_size, void* d_ws, size_t ws_size,
                              hipStream_t stream){
  const float* x    = (const float*)d_in[0];
  const int*   ei   = (const int*)  d_in[1];
  const float* ea   = (const float*)d_in[2];
  const float* wl0  = (const float*)d_in[3];
  const float* wr0  = (const float*)d_in[4];
  const float* we0  = (const float*)d_in[5];
  const float* att0 = (const float*)d_in[6];
  const float* b0   = (const float*)d_in[7];
  const float* wl1  = (const float*)d_in[8];
  const float* wr1  = (const float*)d_in[9];
  const float* we1  = (const float*)d_in[10];
  const float* att1 = (const float*)d_in[11];
  const float* b1   = (const float*)d_in[12];
  const float* wl2  = (const float*)d_in[13];
  const float* wr2  = (const float*)d_in[14];
  const float* we2  = (const float*)d_in[15];
  const float* att2 = (const float*)d_in[16];
  const float* b2   = (const float*)d_in[17];
  const float* wih  = (const float*)d_in[18];
  const float* whh  = (const float*)d_in[19];
  const float* bih  = (const float*)d_in[20];
  const float* bhh  = (const float*)d_in[21];
  const float* fc1w = (const float*)d_in[22];
  const float* fc1b = (const float*)d_in[23];
  const float* fc2w = (const float*)d_in[24];
  const float* fc2b = (const float*)d_in[25];
  float* out = (float*)d_out;

  char* base = (char*)d_ws; size_t cur = 0;
  auto alloc = [&](size_t bytes)->void*{
    cur = (cur + 255) & ~(size_t)255; void* p = base + cur; cur += bytes; return p;
  };
  float* mean_ea = (float*)alloc(8);
  int*   cnt     = (int*)  alloc((size_t)NNODES*4);
  int*   off     = (int*)  alloc((size_t)(NNODES+1)*4);
  int*   cursor  = (int*)  alloc((size_t)NNODES*4);
  int*   csr_src = (int*)  alloc((size_t)NEDGE*4);
  int*   epos    = (int*)  alloc((size_t)NEDGE*4);
  bf16*  eeP     = (bf16*) alloc((size_t)NEDGE*128*2);
  bf16*  XL      = (bf16*) alloc((size_t)80000*128*2);
  bf16*  XR      = (bf16*) alloc((size_t)80000*128*2);
  bf16*  HBUF    = (bf16*) alloc((size_t)80000*128*2);
  float* gates   = (float*)alloc((size_t)40*1024*4);
  float* hst     = (float*)alloc(4*256*4);
  unsigned* whhT2= (unsigned*)alloc((size_t)128*1024*4);
  bf16*  bt1a    = (bf16*) alloc((size_t)128*128*2);
  bf16*  bt1b    = (bf16*) alloc((size_t)128*128*2);
  bf16*  bt2a    = (bf16*) alloc((size_t)32*128*2);
  bf16*  bt2b    = (bf16*) alloc((size_t)32*128*2);

  hipMemsetAsync(cnt,    0, (size_t)NNODES*4, stream);
  hipMemsetAsync(cursor, 0, (size_t)NNODES*4, stream);
  hipMemsetAsync(gates,  0, (size_t)40*1024*4, stream);

  k_mean_ea <<<1,256,0,stream>>>(ea, mean_ea);
  k_count   <<<(NEDGE+255)/256,256,0,stream>>>(ei, cnt);
  k_scan    <<<1,64,0,stream>>>(cnt, off);
  k_scatter <<<(NEDGE+255)/256,256,0,stream>>>(ei, off, cursor, csr_src, epos);
  k_prep_whh<<<512,256,0,stream>>>(whh, whhT2);
  k_wcvt    <<<160,256,0,stream>>>(wl1, wr1, wl2, wr2, bt1a, bt1b, bt2a, bt2b);

  // Layer 0 (Fin=8 -> H=4,C=32)
  k_ee<128> <<<(NEDGE*128)/256,256,0,stream>>>(ea, mean_ea, we0, epos, eeP);
  k_gemm<8,128> <<<10000,256,0,stream>>>(x, wl0, XL);
  k_gemm<8,128> <<<10000,256,0,stream>>>(x, wr0, XR);
  k_edge<4,32> <<<dim3(2000,40),128,0,stream>>>(XL,XR,eeP,off,csr_src,att0,b0,HBUF);

  // Layer 1 (128 -> H=4,C=32), MFMA
  k_ee<128> <<<(NEDGE*128)/256,256,0,stream>>>(ea, mean_ea, we1, epos, eeP);
  k_gemm_mf<128> <<<625,256,0,stream>>>(HBUF, bt1a, XL);
  k_gemm_mf<128> <<<625,256,0,stream>>>(HBUF, bt1b, XR);
  k_edge<4,32> <<<dim3(2000,40),128,0,stream>>>(XL,XR,eeP,off,csr_src,att1,b1,HBUF);

  // Layer 2 (128 -> H=4,C=8), MFMA; output emb bf16 [40][64000] in HBUF
  k_ee<32> <<<(NEDGE*32)/256,256,0,stream>>>(ea, mean_ea, we2, epos, eeP);
  k_gemm_mf<32> <<<625,256,0,stream>>>(HBUF, bt2a, XL);
  k_gemm_mf<32> <<<625,256,0,stream>>>(HBUF, bt2b, XR);
  k_edge<4,8> <<<dim3(500,40),128,0,stream>>>(XL,XR,eeP,off,csr_src,att2,b2,HBUF);

  // gates_x = emb @ w_ih^T
  k_gates2<<<dim3(128,5),256,0,stream>>>(HBUF, wih, gates);

  // fused LSTM (10 steps in one launch)
  k_lstm10<<<4,1024,0,stream>>>(gates, whhT2, bih, bhh, hst);

  k_head<<<4,512,0,stream>>>(hst, fc1w, fc1b, fc2w, fc2b, out);
}

// Round 3
// 759.816 us; speedup vs baseline: 1.6567x; 1.0708x over previous
//
#include <hip/hip_runtime.h>
#include <hip/hip_bf16.h>
#include <math.h>

typedef __hip_bfloat16 bf16;
typedef __attribute__((ext_vector_type(8))) short short8;
typedef __attribute__((ext_vector_type(4))) float f32x4;

#define NNODES 2000
#define NEDGE_IN 16000
#define NEDGE 18000
#define NGRAPH 40

__device__ __forceinline__ float bf2f(bf16 v){ return __bfloat162float(v); }
__device__ __forceinline__ bf16 f2bf(float v){ return __float2bfloat16(v); }

// ---------- setup kernels ----------
__global__ void k_mean_ea(const float* __restrict__ ea, float* __restrict__ mean_ea){
  __shared__ float s0l[256], s1l[256];
  float s0=0.f, s1=0.f;
  for (int e = threadIdx.x; e < NEDGE_IN; e += 256){ s0 += ea[2*e]; s1 += ea[2*e+1]; }
  s0l[threadIdx.x]=s0; s1l[threadIdx.x]=s1; __syncthreads();
  for (int d=128; d>=1; d>>=1){
    if ((int)threadIdx.x < d){ s0l[threadIdx.x]+=s0l[threadIdx.x+d]; s1l[threadIdx.x]+=s1l[threadIdx.x+d]; }
    __syncthreads();
  }
  if (threadIdx.x==0){ mean_ea[0]=s0l[0]/(float)NEDGE_IN; mean_ea[1]=s1l[0]/(float)NEDGE_IN; }
}

__global__ void k_count(const int* __restrict__ ei, int* __restrict__ cnt){
  int e = blockIdx.x*256 + threadIdx.x;
  if (e >= NEDGE) return;
  int d = (e < NEDGE_IN) ? ei[NEDGE_IN + e] : (e - NEDGE_IN);
  atomicAdd(&cnt[d], 1);
}

__global__ void k_scan(const int* __restrict__ cnt, int* __restrict__ off){
  __shared__ int s[2048];
  int lane = threadIdx.x; // 64 threads
  for (int i = lane; i < 2048; i += 64) s[i] = (i < NNODES) ? cnt[i] : 0;
  __syncthreads();
  int base = lane*32, run = 0;
  for (int j=0;j<32;j++){ int t = s[base+j]; s[base+j] = run; run += t; }
  int x = run;
  for (int d=1; d<64; d<<=1){ int y = __shfl_up(x, d); if (lane >= d) x += y; }
  int chunkOff = x - run;
  for (int j=0;j<32;j++){ int idx = base+j; if (idx <= NNODES) off[idx] = chunkOff + s[idx]; }
}

__global__ void k_scatter(const int* __restrict__ ei, const int* __restrict__ off,
                          int* __restrict__ cursor, int* __restrict__ csr_src, int* __restrict__ epos){
  int e = blockIdx.x*256 + threadIdx.x;
  if (e >= NEDGE) return;
  int d, sn;
  if (e < NEDGE_IN){ sn = ei[e]; d = ei[NEDGE_IN+e]; } else { sn = e-NEDGE_IN; d = sn; }
  int p = off[d] + atomicAdd(&cursor[d], 1);
  csr_src[p] = sn;
  epos[e] = p;
}

// pack whh[j][k] -> whhT2[k/2][j] as (bf16(k+1)<<16)|bf16(k)
__global__ void k_prep_whh(const float* __restrict__ whh, unsigned* __restrict__ whhT2){
  int idx = blockIdx.x*256 + threadIdx.x;
  if (idx >= 1024*128) return;
  int j = idx >> 7, kp = idx & 127;
  bf16 lo = f2bf(whh[j*256 + 2*kp]);
  bf16 hi = f2bf(whh[j*256 + 2*kp + 1]);
  unsigned ulo = *(unsigned short*)&lo;
  unsigned uhi = *(unsigned short*)&hi;
  whhT2[kp*1024 + j] = (uhi<<16) | ulo;
}

// convert the 4 layer-1/2 weight matrices W[k][n] (f32) -> BT[n][k] (bf16, row len 128)
__global__ void k_wcvt(const float* __restrict__ w1a, const float* __restrict__ w1b,
                       const float* __restrict__ w2a, const float* __restrict__ w2b,
                       bf16* __restrict__ b1a, bf16* __restrict__ b1b,
                       bf16* __restrict__ b2a, bf16* __restrict__ b2b){
  int idx = blockIdx.x*256 + threadIdx.x; // 40960 total
  if (idx >= 40960) return;
  const float* src; bf16* dst; int n, local;
  if (idx < 16384){ src=w1a; dst=b1a; n=128; local=idx; }
  else if (idx < 32768){ src=w1b; dst=b1b; n=128; local=idx-16384; }
  else if (idx < 36864){ src=w2a; dst=b2a; n=32; local=idx-32768; }
  else { src=w2b; dst=b2b; n=32; local=idx-36864; }
  int k = local / n, c = local % n;
  dst[c*128 + k] = f2bf(src[local]);
}

// ---------- edge-feature projection (into CSR-permuted order, bf16) ----------
template<int HC>
__global__ void k_ee(const float* __restrict__ ea, const float* __restrict__ mean_ea,
                     const float* __restrict__ We, const int* __restrict__ epos,
                     bf16* __restrict__ eeP){
  int idx = blockIdx.x*256 + threadIdx.x;
  if (idx >= NEDGE*HC) return;
  int e = idx / HC, hc = idx % HC;
  float a0, a1;
  if (e < NEDGE_IN){ a0 = ea[2*e]; a1 = ea[2*e+1]; } else { a0 = mean_ea[0]; a1 = mean_ea[1]; }
  float v = a0*We[hc] + a1*We[HC+hc];
  eeP[(size_t)epos[e]*HC + hc] = f2bf(v);
}

// ---------- layer-0 GEMM (K=8, fp32 input), fused Wl+Wr: two outputs ----------
__global__ __launch_bounds__(256) void k_gemm0(const float* __restrict__ X, const float* __restrict__ Wa,
                                               const float* __restrict__ Wb,
                                               bf16* __restrict__ Ya, bf16* __restrict__ Yb){
  __shared__ float Ws[2*8*128];
  for (int i = threadIdx.x; i < 8*128; i += 256){ Ws[i] = Wa[i]; Ws[1024+i] = Wb[i]; }
  __syncthreads();
  int j  = threadIdx.x % 128;
  int rg = threadIdx.x / 128;          // 2 row-groups x 4 rows
  size_t m0 = (size_t)blockIdx.x*8 + (size_t)rg*4;
  const float* x0 = X + m0*8;
  float a0=0.f,a1=0.f,a2=0.f,a3=0.f, b0=0.f,b1=0.f,b2=0.f,b3=0.f;
  #pragma unroll
  for (int k=0;k<8;k++){
    float wa = Ws[k*128 + j], wb = Ws[1024 + k*128 + j];
    float x_0 = x0[k], x_1 = x0[8+k], x_2 = x0[16+k], x_3 = x0[24+k];
    a0 += x_0*wa; a1 += x_1*wa; a2 += x_2*wa; a3 += x_3*wa;
    b0 += x_0*wb; b1 += x_1*wb; b2 += x_2*wb; b3 += x_3*wb;
  }
  bf16* ya = Ya + m0*128 + j;
  bf16* yb = Yb + m0*128 + j;
  ya[0]=f2bf(a0); ya[128]=f2bf(a1); ya[256]=f2bf(a2); ya[384]=f2bf(a3);
  yb[0]=f2bf(b0); yb[128]=f2bf(b1); yb[256]=f2bf(b2); yb[384]=f2bf(b3);
}

// ---------- MFMA GEMM, fused two B matrices: Ya/Yb[M,N] = A[M,128] @ {BTa,BTb} ----------
template<int N>
__global__ __launch_bounds__(256) void k_gemm_mf2(const bf16* __restrict__ A, const bf16* __restrict__ BTa,
                                                  const bf16* __restrict__ BTb,
                                                  bf16* __restrict__ Ya, bf16* __restrict__ Yb){
  const int NT = N/16;
  int lane = threadIdx.x & 63, wv = threadIdx.x >> 6;
  size_t m0 = (size_t)blockIdx.x*128 + (size_t)wv*32;
  int r = lane & 15, kg = lane >> 4;
  const f32x4 zero = {0.f,0.f,0.f,0.f};
  f32x4 acca[2][NT], accb[2][NT];
  #pragma unroll
  for (int s=0;s<2;s++)
    #pragma unroll
    for (int t=0;t<NT;t++){ acca[s][t] = zero; accb[s][t] = zero; }
  #pragma unroll
  for (int c=0;c<4;c++){
    short8 a0 = *(const short8*)(A + (m0 + r)*128 + c*32 + kg*8);
    short8 a1 = *(const short8*)(A + (m0 + 16 + r)*128 + c*32 + kg*8);
    #pragma unroll
    for (int t=0;t<NT;t++){
      short8 ba = *(const short8*)(BTa + (size_t)(t*16 + r)*128 + c*32 + kg*8);
      short8 bb = *(const short8*)(BTb + (size_t)(t*16 + r)*128 + c*32 + kg*8);
      acca[0][t] = __builtin_amdgcn_mfma_f32_16x16x32_bf16(a0, ba, acca[0][t], 0,0,0);
      acca[1][t] = __builtin_amdgcn_mfma_f32_16x16x32_bf16(a1, ba, acca[1][t], 0,0,0);
      accb[0][t] = __builtin_amdgcn_mfma_f32_16x16x32_bf16(a0, bb, accb[0][t], 0,0,0);
      accb[1][t] = __builtin_amdgcn_mfma_f32_16x16x32_bf16(a1, bb, accb[1][t], 0,0,0);
    }
  }
  #pragma unroll
  for (int s=0;s<2;s++)
    #pragma unroll
    for (int t=0;t<NT;t++){
      size_t row = m0 + s*16 + kg*4;
      int col = t*16 + r;
      #pragma unroll
      for (int i=0;i<4;i++){
        Ya[(row+i)*N + col] = f2bf(acca[s][t][i]);
        Yb[(row+i)*N + col] = f2bf(accb[s][t][i]);
      }
    }
}

// ---------- GATv2 edge + softmax (no-max: logits provably small) + aggregate ----------
template<int H, int C>
__global__ __launch_bounds__(128) void k_edge(const bf16* __restrict__ XL, const bf16* __restrict__ XR,
                                              const bf16* __restrict__ eeP, const int* __restrict__ off,
                                              const int* __restrict__ csr_src, const float* __restrict__ att,
                                              const float* __restrict__ bias, bf16* __restrict__ Hout){
  const int HC = H*C;
  const int NPB = 128/HC;
  int hc = threadIdx.x % HC;
  int n  = blockIdx.x*NPB + threadIdx.x/HC;
  int g  = blockIdx.y;
  size_t gbase = (size_t)g*NNODES*HC;
  float xr = bf2f(XR[gbase + (size_t)n*HC + hc]);
  float av = att[hc];
  float srun = 0.f, acc = 0.f;
  int p0 = off[n], p1 = off[n+1];
  for (int p = p0; p < p1; ++p){
    int u = csr_src[p];
    float xl = bf2f(XL[gbase + (size_t)u*HC + hc]);
    float sum = xl + xr + bf2f(eeP[(size_t)p*HC + hc]);
    float m = sum > 0.f ? sum : 0.2f*sum;
    float contrib = m*av;
    #pragma unroll
    for (int d=C/2; d>=1; d>>=1) contrib += __shfl_xor(contrib, d);
    float pe = __expf(contrib);
    srun += pe; acc += pe*xl;
  }
  float o = acc/(srun + 1e-16f) + bias[hc];
  Hout[gbase + (size_t)n*HC + hc] = f2bf(o > 0.f ? o : 0.f);
}

// ---------- gates_x[bt][j] = emb[bt] . w_ih[j]  (LDS-free streaming, 10 k-splits) ----------
__global__ __launch_bounds__(256) void k_gates2(const bf16* __restrict__ emb, const float* __restrict__ wih,
                                                float* __restrict__ gates){
  int lane = threadIdx.x & 63, wv = threadIdx.x >> 6;
  int jbase = blockIdx.x * 8;            // 128 j-groups
  int b0 = wv * 10;                      // 4 waves x 10 bt
  size_t kbase = (size_t)blockIdx.y * 6400;  // 10 k-splits, 25 chunks of 256
  float acc[8][10];
  #pragma unroll
  for (int jj=0;jj<8;jj++)
    #pragma unroll
    for (int b=0;b<10;b++) acc[jj][b] = 0.f;
  const float* wp0 = wih + (size_t)jbase*64000 + kbase + (size_t)lane*4;
  const bf16*  ep0 = emb + (size_t)b0*64000 + kbase + (size_t)lane*4;
  for (int ch=0; ch<25; ++ch){
    size_t koff = (size_t)ch*256;
    float4 w4[8];
    #pragma unroll
    for (int jj=0;jj<8;jj++) w4[jj] = *(const float4*)(wp0 + (size_t)jj*64000 + koff);
    #pragma unroll
    for (int b=0;b<10;b++){
      uint2 u = *(const uint2*)(ep0 + (size_t)b*64000 + koff);
      float e0 = __uint_as_float(u.x << 16);
      float e1 = __uint_as_float(u.x & 0xffff0000u);
      float e2 = __uint_as_float(u.y << 16);
      float e3 = __uint_as_float(u.y & 0xffff0000u);
      #pragma unroll
      for (int jj=0;jj<8;jj++){
        float a = acc[jj][b];
        a = fmaf(w4[jj].x, e0, a);
        a = fmaf(w4[jj].y, e1, a);
        a = fmaf(w4[jj].z, e2, a);
        a = fmaf(w4[jj].w, e3, a);
        acc[jj][b] = a;
      }
    }
  }
  #pragma unroll
  for (int jj=0;jj<8;jj++)
    #pragma unroll
    for (int b=0;b<10;b++){
      float v = acc[jj][b];
      #pragma unroll
      for (int d=1; d<64; d<<=1) v += __shfl_xor(v, d);
      int id = jj*10 + b;
      if (lane == (id & 63))
        atomicAdd(&gates[(size_t)(b0+b)*1024 + jbase + jj], v);
    }
}

// ---------- fused 10-step LSTM: 4 blocks (one per batch) ----------
__global__ __launch_bounds__(1024) void k_lstm10(const float* __restrict__ gates, const unsigned* __restrict__ whhT2,
                                                 const float* __restrict__ bih, const float* __restrict__ bhh,
                                                 float* __restrict__ hst){
  __shared__ float hs[256];
  __shared__ float g[1024];
  int b = blockIdx.x, j = threadIdx.x;
  float c_reg = 0.f;
  if (j < 256) hs[j] = 0.f;
  float bias = bih[j] + bhh[j];
  __syncthreads();
  for (int t=0;t<10;t++){
    float acc = gates[(size_t)(b*10+t)*1024 + j] + bias;
    #pragma unroll 16
    for (int kp=0;kp<128;kp++){
      unsigned u = whhT2[kp*1024 + j];
      float2 h2 = *(const float2*)&hs[2*kp];
      acc = fmaf(__uint_as_float(u<<16), h2.x, acc);
      acc = fmaf(__uint_as_float(u & 0xffff0000u), h2.y, acc);
    }
    g[j] = acc;
    __syncthreads();
    if (j < 256){
      float i_ = g[j], f_ = g[j+256], gg = g[j+512], o_ = g[j+768];
      float si = 1.f/(1.f+__expf(-i_));
      float sf = 1.f/(1.f+__expf(-f_));
      float so = 1.f/(1.f+__expf(-o_));
      c_reg = sf*c_reg + si*tanhf(gg);
      float hn = so*tanhf(c_reg);
      hs[j] = hn;
      if (t==9) hst[b*256+j] = hn;
    }
    __syncthreads();
  }
}

// ---------- head: relu(h) @ fc1 -> relu -> @ fc2 ----------
__global__ __launch_bounds__(512) void k_head(const float* __restrict__ hst, const float* __restrict__ fc1w,
                                              const float* __restrict__ fc1b, const float* __restrict__ fc2w,
                                              const float* __restrict__ fc2b, float* __restrict__ out){
  __shared__ float r[512];
  int b = blockIdx.x, j = threadIdx.x;
  float acc = fc1b[j];
  for (int k=0;k<256;k++){
    float l = hst[b*256+k]; l = l>0.f?l:0.f;
    acc += l * fc1w[k*512 + j];
  }
  float hid = acc>0.f?acc:0.f;
  r[j] = hid * fc2w[j];
  __syncthreads();
  for (int d=256; d>=1; d>>=1){ if (j<d) r[j]+=r[j+d]; __syncthreads(); }
  if (j==0) out[b] = r[0] + fc2b[0];
}

extern "C" void kernel_launch(void* const* d_in, const int* in_sizes, int n_in,
                              void* d_out, int out_size, void* d_ws, size_t ws_size,
                              hipStream_t stream){
  const float* x    = (const float*)d_in[0];
  const int*   ei   = (const int*)  d_in[1];
  const float* ea   = (const float*)d_in[2];
  const float* wl0  = (const float*)d_in[3];
  const float* wr0  = (const float*)d_in[4];
  const float* we0  = (const float*)d_in[5];
  const float* att0 = (const float*)d_in[6];
  const float* b0   = (const float*)d_in[7];
  const float* wl1  = (const float*)d_in[8];
  const float* wr1  = (const float*)d_in[9];
  const float* we1  = (const float*)d_in[10];
  const float* att1 = (const float*)d_in[11];
  const float* b1   = (const float*)d_in[12];
  const float* wl2  = (const float*)d_in[13];
  const float* wr2  = (const float*)d_in[14];
  const float* we2  = (const float*)d_in[15];
  const float* att2 = (const float*)d_in[16];
  const float* b2   = (const float*)d_in[17];
  const float* wih  = (const float*)d_in[18];
  const float* whh  = (const float*)d_in[19];
  const float* bih  = (const float*)d_in[20];
  const float* bhh  = (const float*)d_in[21];
  const float* fc1w = (const float*)d_in[22];
  const float* fc1b = (const float*)d_in[23];
  const float* fc2w = (const float*)d_in[24];
  const float* fc2b = (const float*)d_in[25];
  float* out = (float*)d_out;

  char* base = (char*)d_ws; size_t cur = 0;
  auto alloc = [&](size_t bytes)->void*{
    cur = (cur + 255) & ~(size_t)255; void* p = base + cur; cur += bytes; return p;
  };
  float* mean_ea = (float*)alloc(8);
  int*   cnt     = (int*)  alloc((size_t)NNODES*4);
  int*   off     = (int*)  alloc((size_t)(NNODES+1)*4);
  int*   cursor  = (int*)  alloc((size_t)NNODES*4);
  int*   csr_src = (int*)  alloc((size_t)NEDGE*4);
  int*   epos    = (int*)  alloc((size_t)NEDGE*4);
  bf16*  eeP     = (bf16*) alloc((size_t)NEDGE*128*2);
  bf16*  XL      = (bf16*) alloc((size_t)80000*128*2);
  bf16*  XR      = (bf16*) alloc((size_t)80000*128*2);
  bf16*  HBUF    = (bf16*) alloc((size_t)80000*128*2);
  float* gates   = (float*)alloc((size_t)40*1024*4);
  float* hst     = (float*)alloc(4*256*4);
  unsigned* whhT2= (unsigned*)alloc((size_t)128*1024*4);
  bf16*  bt1a    = (bf16*) alloc((size_t)128*128*2);
  bf16*  bt1b    = (bf16*) alloc((size_t)128*128*2);
  bf16*  bt2a    = (bf16*) alloc((size_t)32*128*2);
  bf16*  bt2b    = (bf16*) alloc((size_t)32*128*2);

  hipMemsetAsync(cnt,    0, (size_t)NNODES*4, stream);
  hipMemsetAsync(cursor, 0, (size_t)NNODES*4, stream);
  hipMemsetAsync(gates,  0, (size_t)40*1024*4, stream);

  k_mean_ea <<<1,256,0,stream>>>(ea, mean_ea);
  k_count   <<<(NEDGE+255)/256,256,0,stream>>>(ei, cnt);
  k_scan    <<<1,64,0,stream>>>(cnt, off);
  k_scatter <<<(NEDGE+255)/256,256,0,stream>>>(ei, off, cursor, csr_src, epos);
  k_prep_whh<<<512,256,0,stream>>>(whh, whhT2);
  k_wcvt    <<<160,256,0,stream>>>(wl1, wr1, wl2, wr2, bt1a, bt1b, bt2a, bt2b);

  // Layer 0 (Fin=8 -> H=4,C=32), fused Wl+Wr
  k_ee<128> <<<(NEDGE*128)/256,256,0,stream>>>(ea, mean_ea, we0, epos, eeP);
  k_gemm0   <<<10000,256,0,stream>>>(x, wl0, wr0, XL, XR);
  k_edge<4,32> <<<dim3(2000,40),128,0,stream>>>(XL,XR,eeP,off,csr_src,att0,b0,HBUF);

  // Layer 1 (128 -> H=4,C=32), fused MFMA pair
  k_ee<128> <<<(NEDGE*128)/256,256,0,stream>>>(ea, mean_ea, we1, epos, eeP);
  k_gemm_mf2<128> <<<625,256,0,stream>>>(HBUF, bt1a, bt1b, XL, XR);
  k_edge<4,32> <<<dim3(2000,40),128,0,stream>>>(XL,XR,eeP,off,csr_src,att1,b1,HBUF);

  // Layer 2 (128 -> H=4,C=8), fused MFMA pair; output emb bf16 [40][64000] in HBUF
  k_ee<32> <<<(NEDGE*32)/256,256,0,stream>>>(ea, mean_ea, we2, epos, eeP);
  k_gemm_mf2<32> <<<625,256,0,stream>>>(HBUF, bt2a, bt2b, XL, XR);
  k_edge<4,8> <<<dim3(500,40),128,0,stream>>>(XL,XR,eeP,off,csr_src,att2,b2,HBUF);

  // gates_x = emb @ w_ih^T  (1280 blocks: 128 j-groups x 10 k-splits)
  k_gates2<<<dim3(128,10),256,0,stream>>>(HBUF, wih, gates);

  // fused LSTM (10 steps in one launch)
  k_lstm10<<<4,1024,0,stream>>>(gates, whhT2, bih, bhh, hst);

  k_head<<<4,512,0,stream>>>(hst, fc1w, fc1b, fc2w, fc2b, out);
}

// Round 4
// 549.852 us; speedup vs baseline: 2.2893x; 1.3819x over previous
//
#include <hip/hip_runtime.h>
#include <hip/hip_bf16.h>
#include <math.h>

typedef __hip_bfloat16 bf16;
typedef __attribute__((ext_vector_type(8))) short short8;
typedef __attribute__((ext_vector_type(4))) float f32x4;

#define NNODES 2000
#define NEDGE_IN 16000
#define NEDGE 18000
#define NGRAPH 40

__device__ __forceinline__ float bf2f(bf16 v){ return __bfloat162float(v); }
__device__ __forceinline__ bf16 f2bf(float v){ return __float2bfloat16(v); }
__device__ __forceinline__ short bfbits(float v){ bf16 t = __float2bfloat16(v); return *reinterpret_cast<short*>(&t); }

// ---------- setup kernels ----------
__global__ void k_mean_ea(const float* __restrict__ ea, float* __restrict__ mean_ea){
  __shared__ float s0l[256], s1l[256];
  float s0=0.f, s1=0.f;
  for (int e = threadIdx.x; e < NEDGE_IN; e += 256){ s0 += ea[2*e]; s1 += ea[2*e+1]; }
  s0l[threadIdx.x]=s0; s1l[threadIdx.x]=s1; __syncthreads();
  for (int d=128; d>=1; d>>=1){
    if ((int)threadIdx.x < d){ s0l[threadIdx.x]+=s0l[threadIdx.x+d]; s1l[threadIdx.x]+=s1l[threadIdx.x+d]; }
    __syncthreads();
  }
  if (threadIdx.x==0){ mean_ea[0]=s0l[0]/(float)NEDGE_IN; mean_ea[1]=s1l[0]/(float)NEDGE_IN; }
}

__global__ void k_count(const int* __restrict__ ei, int* __restrict__ cnt){
  int e = blockIdx.x*256 + threadIdx.x;
  if (e >= NEDGE) return;
  int d = (e < NEDGE_IN) ? ei[NEDGE_IN + e] : (e - NEDGE_IN);
  atomicAdd(&cnt[d], 1);
}

__global__ void k_scan(const int* __restrict__ cnt, int* __restrict__ off){
  __shared__ int s[2048];
  int lane = threadIdx.x; // 64 threads
  for (int i = lane; i < 2048; i += 64) s[i] = (i < NNODES) ? cnt[i] : 0;
  __syncthreads();
  int base = lane*32, run = 0;
  for (int j=0;j<32;j++){ int t = s[base+j]; s[base+j] = run; run += t; }
  int x = run;
  for (int d=1; d<64; d<<=1){ int y = __shfl_up(x, d); if (lane >= d) x += y; }
  int chunkOff = x - run;
  for (int j=0;j<32;j++){ int idx = base+j; if (idx <= NNODES) off[idx] = chunkOff + s[idx]; }
}

// scatter edges into CSR order; also permute raw edge_attr (with self-loop mean fill)
__global__ void k_scatter(const int* __restrict__ ei, const int* __restrict__ off,
                          int* __restrict__ cursor, const float* __restrict__ ea,
                          const float* __restrict__ mean_ea,
                          int* __restrict__ csr_src, float2* __restrict__ eaP){
  int e = blockIdx.x*256 + threadIdx.x;
  if (e >= NEDGE) return;
  int d, sn; float2 a;
  if (e < NEDGE_IN){ sn = ei[e]; d = ei[NEDGE_IN+e]; a = ((const float2*)ea)[e]; }
  else { sn = e-NEDGE_IN; d = sn; a.x = mean_ea[0]; a.y = mean_ea[1]; }
  int p = off[d] + atomicAdd(&cursor[d], 1);
  csr_src[p] = sn;
  eaP[p] = a;
}

// pack whh[j][k] -> whhT2[k/2][j] as (bf16(k+1)<<16)|bf16(k)
__global__ void k_prep_whh(const float* __restrict__ whh, unsigned* __restrict__ whhT2){
  int idx = blockIdx.x*256 + threadIdx.x;
  if (idx >= 1024*128) return;
  int j = idx >> 7, kp = idx & 127;
  unsigned ulo = (unsigned)(unsigned short)bfbits(whh[j*256 + 2*kp]);
  unsigned uhi = (unsigned)(unsigned short)bfbits(whh[j*256 + 2*kp + 1]);
  whhT2[kp*1024 + j] = (uhi<<16) | ulo;
}

// convert the 4 layer-1/2 weight matrices W[k][n] (f32) -> BT[n][k] (bf16, row len 128)
__global__ void k_wcvt(const float* __restrict__ w1a, const float* __restrict__ w1b,
                       const float* __restrict__ w2a, const float* __restrict__ w2b,
                       bf16* __restrict__ b1a, bf16* __restrict__ b1b,
                       bf16* __restrict__ b2a, bf16* __restrict__ b2b){
  int idx = blockIdx.x*256 + threadIdx.x; // 40960 total
  if (idx >= 40960) return;
  const float* src; bf16* dst; int n, local;
  if (idx < 16384){ src=w1a; dst=b1a; n=128; local=idx; }
  else if (idx < 32768){ src=w1b; dst=b1b; n=128; local=idx-16384; }
  else if (idx < 36864){ src=w2a; dst=b2a; n=32; local=idx-32768; }
  else { src=w2b; dst=b2b; n=32; local=idx-36864; }
  int k = local / n, c = local % n;
  dst[c*128 + k] = f2bf(src[local]);
}

// ---------- layer-0 GEMM (K=8, fp32 input), fused Wl+Wr: two outputs ----------
__global__ __launch_bounds__(256) void k_gemm0(const float* __restrict__ X, const float* __restrict__ Wa,
                                               const float* __restrict__ Wb,
                                               bf16* __restrict__ Ya, bf16* __restrict__ Yb){
  __shared__ float Ws[2*8*128];
  for (int i = threadIdx.x; i < 8*128; i += 256){ Ws[i] = Wa[i]; Ws[1024+i] = Wb[i]; }
  __syncthreads();
  int j  = threadIdx.x % 128;
  int rg = threadIdx.x / 128;          // 2 row-groups x 4 rows
  size_t m0 = (size_t)blockIdx.x*8 + (size_t)rg*4;
  const float* x0 = X + m0*8;
  float a0=0.f,a1=0.f,a2=0.f,a3=0.f, b0=0.f,b1=0.f,b2=0.f,b3=0.f;
  #pragma unroll
  for (int k=0;k<8;k++){
    float wa = Ws[k*128 + j], wb = Ws[1024 + k*128 + j];
    float x_0 = x0[k], x_1 = x0[8+k], x_2 = x0[16+k], x_3 = x0[24+k];
    a0 += x_0*wa; a1 += x_1*wa; a2 += x_2*wa; a3 += x_3*wa;
    b0 += x_0*wb; b1 += x_1*wb; b2 += x_2*wb; b3 += x_3*wb;
  }
  bf16* ya = Ya + m0*128 + j;
  bf16* yb = Yb + m0*128 + j;
  ya[0]=f2bf(a0); ya[128]=f2bf(a1); ya[256]=f2bf(a2); ya[384]=f2bf(a3);
  yb[0]=f2bf(b0); yb[128]=f2bf(b1); yb[256]=f2bf(b2); yb[384]=f2bf(b3);
}

// ---------- MFMA GEMM, fused two B matrices: Ya/Yb[M,N] = A[M,128] @ {BTa,BTb} ----------
template<int N>
__global__ __launch_bounds__(256) void k_gemm_mf2(const bf16* __restrict__ A, const bf16* __restrict__ BTa,
                                                  const bf16* __restrict__ BTb,
                                                  bf16* __restrict__ Ya, bf16* __restrict__ Yb){
  const int NT = N/16;
  int lane = threadIdx.x & 63, wv = threadIdx.x >> 6;
  size_t m0 = (size_t)blockIdx.x*128 + (size_t)wv*32;
  int r = lane & 15, kg = lane >> 4;
  const f32x4 zero = {0.f,0.f,0.f,0.f};
  f32x4 acca[2][NT], accb[2][NT];
  #pragma unroll
  for (int s=0;s<2;s++)
    #pragma unroll
    for (int t=0;t<NT;t++){ acca[s][t] = zero; accb[s][t] = zero; }
  #pragma unroll
  for (int c=0;c<4;c++){
    short8 a0 = *(const short8*)(A + (m0 + r)*128 + c*32 + kg*8);
    short8 a1 = *(const short8*)(A + (m0 + 16 + r)*128 + c*32 + kg*8);
    #pragma unroll
    for (int t=0;t<NT;t++){
      short8 ba = *(const short8*)(BTa + (size_t)(t*16 + r)*128 + c*32 + kg*8);
      short8 bb = *(const short8*)(BTb + (size_t)(t*16 + r)*128 + c*32 + kg*8);
      acca[0][t] = __builtin_amdgcn_mfma_f32_16x16x32_bf16(a0, ba, acca[0][t], 0,0,0);
      acca[1][t] = __builtin_amdgcn_mfma_f32_16x16x32_bf16(a1, ba, acca[1][t], 0,0,0);
      accb[0][t] = __builtin_amdgcn_mfma_f32_16x16x32_bf16(a0, bb, accb[0][t], 0,0,0);
      accb[1][t] = __builtin_amdgcn_mfma_f32_16x16x32_bf16(a1, bb, accb[1][t], 0,0,0);
    }
  }
  #pragma unroll
  for (int s=0;s<2;s++)
    #pragma unroll
    for (int t=0;t<NT;t++){
      size_t row = m0 + s*16 + kg*4;
      int col = t*16 + r;
      #pragma unroll
      for (int i=0;i<4;i++){
        Ya[(row+i)*N + col] = f2bf(acca[s][t][i]);
        Yb[(row+i)*N + col] = f2bf(accb[s][t][i]);
      }
    }
}

// ---------- GATv2 edge + softmax + aggregate + bias + relu (ee fused, unroll-2) ----------
template<int H, int C>
__global__ __launch_bounds__(128) void k_edge(const bf16* __restrict__ XL, const bf16* __restrict__ XR,
                                              const float2* __restrict__ eaP, const int* __restrict__ off,
                                              const int* __restrict__ csr_src, const float* __restrict__ att,
                                              const float* __restrict__ We, const float* __restrict__ bias,
                                              bf16* __restrict__ Hout){
  const int HC = H*C;
  const int NPB = 128/HC;
  int hc = threadIdx.x % HC;
  int n  = blockIdx.x*NPB + threadIdx.x/HC;
  int g  = blockIdx.y;
  size_t gbase = (size_t)g*NNODES*HC;
  float xr = bf2f(XR[gbase + (size_t)n*HC + hc]);
  float av = att[hc];
  float w0 = We[hc], w1 = We[HC+hc];
  float srun = 0.f, acc = 0.f;
  int p0 = off[n], p1 = off[n+1];
  int p = p0;
  for (; p+2 <= p1; p += 2){
    int u0 = csr_src[p], u1 = csr_src[p+1];
    float2 e0 = eaP[p], e1 = eaP[p+1];
    float xl0 = bf2f(XL[gbase + (size_t)u0*HC + hc]);
    float xl1 = bf2f(XL[gbase + (size_t)u1*HC + hc]);
    float s0 = xl0 + xr + e0.x*w0 + e0.y*w1;
    float s1 = xl1 + xr + e1.x*w0 + e1.y*w1;
    float m0 = s0 > 0.f ? s0 : 0.2f*s0;
    float m1 = s1 > 0.f ? s1 : 0.2f*s1;
    float c0 = m0*av, c1 = m1*av;
    #pragma unroll
    for (int d=C/2; d>=1; d>>=1){ c0 += __shfl_xor(c0, d); c1 += __shfl_xor(c1, d); }
    float pe0 = __expf(c0), pe1 = __expf(c1);
    srun += pe0 + pe1;
    acc = fmaf(pe0, xl0, fmaf(pe1, xl1, acc));
  }
  if (p < p1){
    int u0 = csr_src[p];
    float2 e0 = eaP[p];
    float xl0 = bf2f(XL[gbase + (size_t)u0*HC + hc]);
    float s0 = xl0 + xr + e0.x*w0 + e0.y*w1;
    float m0 = s0 > 0.f ? s0 : 0.2f*s0;
    float c0 = m0*av;
    #pragma unroll
    for (int d=C/2; d>=1; d>>=1) c0 += __shfl_xor(c0, d);
    float pe0 = __expf(c0);
    srun += pe0; acc = fmaf(pe0, xl0, acc);
  }
  float o = acc/(srun + 1e-16f) + bias[hc];
  Hout[gbase + (size_t)n*HC + hc] = f2bf(o > 0.f ? o : 0.f);
}

// ---------- gates_x[bt][j] = emb[bt] . w_ih[j] via MFMA (w cvt to bf16 in-reg) ----------
// grid (16 j-blocks, 40 k-splits), 256 thr = 4 waves; wave -> j-tile of 16; bt = 3 M-tiles of 16
#define GATES_KS 40
__global__ __launch_bounds__(256) void k_gates_mf(const bf16* __restrict__ emb, const float* __restrict__ wih,
                                                  float* __restrict__ gates){
  const int nk = 2000/GATES_KS;   // 50 k-steps of 32
  int lane = threadIdx.x & 63, wv = threadIdx.x >> 6;
  int r = lane & 15, kg = lane >> 4;
  int j0 = (blockIdx.x*4 + wv)*16;
  int k0 = blockIdx.y*nk*32;
  const f32x4 zero = {0.f,0.f,0.f,0.f};
  f32x4 acc0 = zero, acc1 = zero, acc2 = zero;
  const float* wrow = wih + (size_t)(j0 + r)*64000;
  const bf16*  e0p  = emb + (size_t)r*64000;
  const bf16*  e1p  = emb + (size_t)(16+r)*64000;
  const bf16*  e2p  = emb + (size_t)(32+r)*64000;  // rows 40-47 are garbage-safe (unwritten C rows)
  #pragma unroll 2
  for (int s=0; s<nk; ++s){
    int k = k0 + s*32 + kg*8;
    float4 wa = *(const float4*)(wrow + k);
    float4 wb = *(const float4*)(wrow + k + 4);
    short8 bfr;
    bfr[0]=bfbits(wa.x); bfr[1]=bfbits(wa.y); bfr[2]=bfbits(wa.z); bfr[3]=bfbits(wa.w);
    bfr[4]=bfbits(wb.x); bfr[5]=bfbits(wb.y); bfr[6]=bfbits(wb.z); bfr[7]=bfbits(wb.w);
    short8 a0 = *(const short8*)(e0p + k);
    short8 a1 = *(const short8*)(e1p + k);
    short8 a2 = *(const short8*)(e2p + k);
    acc0 = __builtin_amdgcn_mfma_f32_16x16x32_bf16(a0, bfr, acc0, 0,0,0);
    acc1 = __builtin_amdgcn_mfma_f32_16x16x32_bf16(a1, bfr, acc1, 0,0,0);
    acc2 = __builtin_amdgcn_mfma_f32_16x16x32_bf16(a2, bfr, acc2, 0,0,0);
  }
  int col = j0 + r;
  #pragma unroll
  for (int i=0;i<4;i++){
    int row = kg*4 + i;
    atomicAdd(&gates[(size_t)row*1024 + col], acc0[i]);
    atomicAdd(&gates[(size_t)(row+16)*1024 + col], acc1[i]);
    if (row + 32 < 40) atomicAdd(&gates[(size_t)(row+32)*1024 + col], acc2[i]);
  }
}

// ---------- fused 10-step LSTM: 4 blocks (one per batch) ----------
__global__ __launch_bounds__(1024) void k_lstm10(const float* __restrict__ gates, const unsigned* __restrict__ whhT2,
                                                 const float* __restrict__ bih, const float* __restrict__ bhh,
                                                 float* __restrict__ hst){
  __shared__ float hs[256];
  __shared__ float g[1024];
  int b = blockIdx.x, j = threadIdx.x;
  float c_reg = 0.f;
  if (j < 256) hs[j] = 0.f;
  float bias = bih[j] + bhh[j];
  __syncthreads();
  for (int t=0;t<10;t++){
    float acc = gates[(size_t)(b*10+t)*1024 + j] + bias;
    #pragma unroll 16
    for (int kp=0;kp<128;kp++){
      unsigned u = whhT2[kp*1024 + j];
      float2 h2 = *(const float2*)&hs[2*kp];
      acc = fmaf(__uint_as_float(u<<16), h2.x, acc);
      acc = fmaf(__uint_as_float(u & 0xffff0000u), h2.y, acc);
    }
    g[j] = acc;
    __syncthreads();
    if (j < 256){
      float i_ = g[j], f_ = g[j+256], gg = g[j+512], o_ = g[j+768];
      float si = 1.f/(1.f+__expf(-i_));
      float sf = 1.f/(1.f+__expf(-f_));
      float so = 1.f/(1.f+__expf(-o_));
      c_reg = sf*c_reg + si*tanhf(gg);
      float hn = so*tanhf(c_reg);
      hs[j] = hn;
      if (t==9) hst[b*256+j] = hn;
    }
    __syncthreads();
  }
}

// ---------- head: relu(h) @ fc1 -> relu -> @ fc2 ----------
__global__ __launch_bounds__(512) void k_head(const float* __restrict__ hst, const float* __restrict__ fc1w,
                                              const float* __restrict__ fc1b, const float* __restrict__ fc2w,
                                              const float* __restrict__ fc2b, float* __restrict__ out){
  __shared__ float r[512];
  int b = blockIdx.x, j = threadIdx.x;
  float acc = fc1b[j];
  for (int k=0;k<256;k++){
    float l = hst[b*256+k]; l = l>0.f?l:0.f;
    acc += l * fc1w[k*512 + j];
  }
  float hid = acc>0.f?acc:0.f;
  r[j] = hid * fc2w[j];
  __syncthreads();
  for (int d=256; d>=1; d>>=1){ if (j<d) r[j]+=r[j+d]; __syncthreads(); }
  if (j==0) out[b] = r[0] + fc2b[0];
}

extern "C" void kernel_launch(void* const* d_in, const int* in_sizes, int n_in,
                              void* d_out, int out_size, void* d_ws, size_t ws_size,
                              hipStream_t stream){
  const float* x    = (const float*)d_in[0];
  const int*   ei   = (const int*)  d_in[1];
  const float* ea   = (const float*)d_in[2];
  const float* wl0  = (const float*)d_in[3];
  const float* wr0  = (const float*)d_in[4];
  const float* we0  = (const float*)d_in[5];
  const float* att0 = (const float*)d_in[6];
  const float* b0   = (const float*)d_in[7];
  const float* wl1  = (const float*)d_in[8];
  const float* wr1  = (const float*)d_in[9];
  const float* we1  = (const float*)d_in[10];
  const float* att1 = (const float*)d_in[11];
  const float* b1   = (const float*)d_in[12];
  const float* wl2  = (const float*)d_in[13];
  const float* wr2  = (const float*)d_in[14];
  const float* we2  = (const float*)d_in[15];
  const float* att2 = (const float*)d_in[16];
  const float* b2   = (const float*)d_in[17];
  const float* wih  = (const float*)d_in[18];
  const float* whh  = (const float*)d_in[19];
  const float* bih  = (const float*)d_in[20];
  const float* bhh  = (const float*)d_in[21];
  const float* fc1w = (const float*)d_in[22];
  const float* fc1b = (const float*)d_in[23];
  const float* fc2w = (const float*)d_in[24];
  const float* fc2b = (const float*)d_in[25];
  float* out = (float*)d_out;

  char* base = (char*)d_ws; size_t cur = 0;
  auto alloc = [&](size_t bytes)->void*{
    cur = (cur + 255) & ~(size_t)255; void* p = base + cur; cur += bytes; return p;
  };
  float* mean_ea = (float*)alloc(8);
  int*   cnt     = (int*)  alloc((size_t)NNODES*4);
  int*   off     = (int*)  alloc((size_t)(NNODES+1)*4);
  int*   cursor  = (int*)  alloc((size_t)NNODES*4);
  int*   csr_src = (int*)  alloc((size_t)NEDGE*4);
  float2* eaP    = (float2*)alloc((size_t)NEDGE*8);
  bf16*  XL      = (bf16*) alloc((size_t)80000*128*2);
  bf16*  XR      = (bf16*) alloc((size_t)80000*128*2);
  bf16*  HBUF    = (bf16*) alloc((size_t)80000*128*2);
  float* gates   = (float*)alloc((size_t)40*1024*4);
  float* hst     = (float*)alloc(4*256*4);
  unsigned* whhT2= (unsigned*)alloc((size_t)128*1024*4);
  bf16*  bt1a    = (bf16*) alloc((size_t)128*128*2);
  bf16*  bt1b    = (bf16*) alloc((size_t)128*128*2);
  bf16*  bt2a    = (bf16*) alloc((size_t)32*128*2);
  bf16*  bt2b    = (bf16*) alloc((size_t)32*128*2);

  hipMemsetAsync(cnt,    0, (size_t)NNODES*4, stream);
  hipMemsetAsync(cursor, 0, (size_t)NNODES*4, stream);
  hipMemsetAsync(gates,  0, (size_t)40*1024*4, stream);

  k_mean_ea <<<1,256,0,stream>>>(ea, mean_ea);
  k_count   <<<(NEDGE+255)/256,256,0,stream>>>(ei, cnt);
  k_scan    <<<1,64,0,stream>>>(cnt, off);
  k_scatter <<<(NEDGE+255)/256,256,0,stream>>>(ei, off, cursor, ea, mean_ea, csr_src, eaP);
  k_prep_whh<<<512,256,0,stream>>>(whh, whhT2);
  k_wcvt    <<<160,256,0,stream>>>(wl1, wr1, wl2, wr2, bt1a, bt1b, bt2a, bt2b);

  // Layer 0 (Fin=8 -> H=4,C=32), fused Wl+Wr
  k_gemm0   <<<10000,256,0,stream>>>(x, wl0, wr0, XL, XR);
  k_edge<4,32> <<<dim3(2000,40),128,0,stream>>>(XL,XR,eaP,off,csr_src,att0,we0,b0,HBUF);

  // Layer 1 (128 -> H=4,C=32), fused MFMA pair
  k_gemm_mf2<128> <<<625,256,0,stream>>>(HBUF, bt1a, bt1b, XL, XR);
  k_edge<4,32> <<<dim3(2000,40),128,0,stream>>>(XL,XR,eaP,off,csr_src,att1,we1,b1,HBUF);

  // Layer 2 (128 -> H=4,C=8), fused MFMA pair; output emb bf16 [40][64000] in HBUF
  k_gemm_mf2<32> <<<625,256,0,stream>>>(HBUF, bt2a, bt2b, XL, XR);
  k_edge<4,8> <<<dim3(500,40),128,0,stream>>>(XL,XR,eaP,off,csr_src,att2,we2,b2,HBUF);

  // gates_x = emb @ w_ih^T via MFMA (in-register f32->bf16 of w_ih)
  k_gates_mf<<<dim3(16,GATES_KS),256,0,stream>>>(HBUF, wih, gates);

  // fused LSTM (10 steps in one launch)
  k_lstm10<<<4,1024,0,stream>>>(gates, whhT2, bih, bhh, hst);

  k_head<<<4,512,0,stream>>>(hst, fc1w, fc1b, fc2w, fc2b, out);
}

// Round 5
// 430.415 us; speedup vs baseline: 2.9246x; 1.2775x over previous
//
#include <hip/hip_runtime.h>
#include <hip/hip_bf16.h>
#include <math.h>

typedef __hip_bfloat16 bf16;
typedef __attribute__((ext_vector_type(8))) short short8;
typedef __attribute__((ext_vector_type(4))) float f32x4;

#define NNODES 2000
#define NEDGE_IN 16000
#define NEDGE 18000
#define NGRAPH 40

__device__ __forceinline__ float bf2f(bf16 v){ return __bfloat162float(v); }
__device__ __forceinline__ bf16 f2bf(float v){ return __float2bfloat16(v); }
__device__ __forceinline__ short bfbits(float v){ bf16 t = __float2bfloat16(v); return *reinterpret_cast<short*>(&t); }

// ---------- fused setup: mean_ea | prep_whh | wcvt | zero(cnt,cursor,gates) ----------
__global__ __launch_bounds__(256) void k_setup(const float* __restrict__ ea, float* __restrict__ mean_ea,
                        const float* __restrict__ whh, unsigned* __restrict__ whhT2,
                        const float* __restrict__ w1a, const float* __restrict__ w1b,
                        const float* __restrict__ w2a, const float* __restrict__ w2b,
                        bf16* __restrict__ b1a, bf16* __restrict__ b1b,
                        bf16* __restrict__ b2a, bf16* __restrict__ b2b,
                        int* __restrict__ cnt, int* __restrict__ cursor, float* __restrict__ gates){
  int bb = blockIdx.x, tid = threadIdx.x;
  if (bb == 0){
    __shared__ float s0l[256], s1l[256];
    float s0=0.f, s1=0.f;
    for (int e = tid; e < NEDGE_IN; e += 256){ s0 += ea[2*e]; s1 += ea[2*e+1]; }
    s0l[tid]=s0; s1l[tid]=s1; __syncthreads();
    for (int d=128; d>=1; d>>=1){
      if (tid < d){ s0l[tid]+=s0l[tid+d]; s1l[tid]+=s1l[tid+d]; }
      __syncthreads();
    }
    if (tid==0){ mean_ea[0]=s0l[0]/(float)NEDGE_IN; mean_ea[1]=s1l[0]/(float)NEDGE_IN; }
  } else if (bb < 513){
    int idx = (bb-1)*256 + tid;           // 1024*128
    int j = idx >> 7, kp = idx & 127;
    unsigned ulo = (unsigned)(unsigned short)bfbits(whh[j*256 + 2*kp]);
    unsigned uhi = (unsigned)(unsigned short)bfbits(whh[j*256 + 2*kp + 1]);
    whhT2[kp*1024 + j] = (uhi<<16) | ulo;
  } else if (bb < 673){
    int idx = (bb-513)*256 + tid;         // 40960
    const float* src; bf16* dst; int n, local;
    if (idx < 16384){ src=w1a; dst=b1a; n=128; local=idx; }
    else if (idx < 32768){ src=w1b; dst=b1b; n=128; local=idx-16384; }
    else if (idx < 36864){ src=w2a; dst=b2a; n=32; local=idx-32768; }
    else { src=w2b; dst=b2b; n=32; local=idx-36864; }
    int k = local / n, c = local % n;
    dst[c*128 + k] = f2bf(src[local]);
  } else {
    int idx = (bb-673)*256 + tid;         // 2000 + 2000 + 40960 = 44960
    if (idx < 2000) cnt[idx] = 0;
    else if (idx < 4000) cursor[idx-2000] = 0;
    else if (idx < 44960) gates[idx-4000] = 0.f;
  }
}

__global__ void k_count(const int* __restrict__ ei, int* __restrict__ cnt){
  int e = blockIdx.x*256 + threadIdx.x;
  if (e >= NEDGE) return;
  int d = (e < NEDGE_IN) ? ei[NEDGE_IN + e] : (e - NEDGE_IN);
  atomicAdd(&cnt[d], 1);
}

__global__ void k_scan(const int* __restrict__ cnt, int* __restrict__ off){
  __shared__ int s[2048];
  int lane = threadIdx.x; // 64 threads
  for (int i = lane; i < 2048; i += 64) s[i] = (i < NNODES) ? cnt[i] : 0;
  __syncthreads();
  int base = lane*32, run = 0;
  for (int j=0;j<32;j++){ int t = s[base+j]; s[base+j] = run; run += t; }
  int x = run;
  for (int d=1; d<64; d<<=1){ int y = __shfl_up(x, d); if (lane >= d) x += y; }
  int chunkOff = x - run;
  for (int j=0;j<32;j++){ int idx = base+j; if (idx <= NNODES) off[idx] = chunkOff + s[idx]; }
}

// scatter edges into CSR order; also permute raw edge_attr (with self-loop mean fill)
__global__ void k_scatter(const int* __restrict__ ei, const int* __restrict__ off,
                          int* __restrict__ cursor, const float* __restrict__ ea,
                          const float* __restrict__ mean_ea,
                          int* __restrict__ csr_src, float2* __restrict__ eaP){
  int e = blockIdx.x*256 + threadIdx.x;
  if (e >= NEDGE) return;
  int d, sn; float2 a;
  if (e < NEDGE_IN){ sn = ei[e]; d = ei[NEDGE_IN+e]; a = ((const float2*)ea)[e]; }
  else { sn = e-NEDGE_IN; d = sn; a.x = mean_ea[0]; a.y = mean_ea[1]; }
  int p = off[d] + atomicAdd(&cursor[d], 1);
  csr_src[p] = sn;
  eaP[p] = a;
}

// ---------- layer-0 GEMM (K=8, fp32 input), fused Wl+Wr: two outputs ----------
__global__ __launch_bounds__(256) void k_gemm0(const float* __restrict__ X, const float* __restrict__ Wa,
                                               const float* __restrict__ Wb,
                                               bf16* __restrict__ Ya, bf16* __restrict__ Yb){
  __shared__ float Ws[2*8*128];
  for (int i = threadIdx.x; i < 8*128; i += 256){ Ws[i] = Wa[i]; Ws[1024+i] = Wb[i]; }
  __syncthreads();
  int j  = threadIdx.x % 128;
  int rg = threadIdx.x / 128;          // 2 row-groups x 4 rows
  size_t m0 = (size_t)blockIdx.x*8 + (size_t)rg*4;
  const float* x0 = X + m0*8;
  float a0=0.f,a1=0.f,a2=0.f,a3=0.f, b0=0.f,b1=0.f,b2=0.f,b3=0.f;
  #pragma unroll
  for (int k=0;k<8;k++){
    float wa = Ws[k*128 + j], wb = Ws[1024 + k*128 + j];
    float x_0 = x0[k], x_1 = x0[8+k], x_2 = x0[16+k], x_3 = x0[24+k];
    a0 += x_0*wa; a1 += x_1*wa; a2 += x_2*wa; a3 += x_3*wa;
    b0 += x_0*wb; b1 += x_1*wb; b2 += x_2*wb; b3 += x_3*wb;
  }
  bf16* ya = Ya + m0*128 + j;
  bf16* yb = Yb + m0*128 + j;
  ya[0]=f2bf(a0); ya[128]=f2bf(a1); ya[256]=f2bf(a2); ya[384]=f2bf(a3);
  yb[0]=f2bf(b0); yb[128]=f2bf(b1); yb[256]=f2bf(b2); yb[384]=f2bf(b3);
}

// ---------- MFMA GEMM, fused two B matrices: Ya/Yb[M,N] = A[M,128] @ {BTa,BTb} ----------
template<int N>
__global__ __launch_bounds__(256) void k_gemm_mf2(const bf16* __restrict__ A, const bf16* __restrict__ BTa,
                                                  const bf16* __restrict__ BTb,
                                                  bf16* __restrict__ Ya, bf16* __restrict__ Yb){
  const int NT = N/16;
  int lane = threadIdx.x & 63, wv = threadIdx.x >> 6;
  size_t m0 = (size_t)blockIdx.x*128 + (size_t)wv*32;
  int r = lane & 15, kg = lane >> 4;
  const f32x4 zero = {0.f,0.f,0.f,0.f};
  f32x4 acca[2][NT], accb[2][NT];
  #pragma unroll
  for (int s=0;s<2;s++)
    #pragma unroll
    for (int t=0;t<NT;t++){ acca[s][t] = zero; accb[s][t] = zero; }
  #pragma unroll
  for (int c=0;c<4;c++){
    short8 a0 = *(const short8*)(A + (m0 + r)*128 + c*32 + kg*8);
    short8 a1 = *(const short8*)(A + (m0 + 16 + r)*128 + c*32 + kg*8);
    #pragma unroll
    for (int t=0;t<NT;t++){
      short8 ba = *(const short8*)(BTa + (size_t)(t*16 + r)*128 + c*32 + kg*8);
      short8 bb = *(const short8*)(BTb + (size_t)(t*16 + r)*128 + c*32 + kg*8);
      acca[0][t] = __builtin_amdgcn_mfma_f32_16x16x32_bf16(a0, ba, acca[0][t], 0,0,0);
      acca[1][t] = __builtin_amdgcn_mfma_f32_16x16x32_bf16(a1, ba, acca[1][t], 0,0,0);
      accb[0][t] = __builtin_amdgcn_mfma_f32_16x16x32_bf16(a0, bb, accb[0][t], 0,0,0);
      accb[1][t] = __builtin_amdgcn_mfma_f32_16x16x32_bf16(a1, bb, accb[1][t], 0,0,0);
    }
  }
  #pragma unroll
  for (int s=0;s<2;s++)
    #pragma unroll
    for (int t=0;t<NT;t++){
      size_t row = m0 + s*16 + kg*4;
      int col = t*16 + r;
      #pragma unroll
      for (int i=0;i<4;i++){
        Ya[(row+i)*N + col] = f2bf(acca[s][t][i]);
        Yb[(row+i)*N + col] = f2bf(accb[s][t][i]);
      }
    }
}

// ---------- GATv2 edge kernel, channel-pair packed: lane = 2 channels ----------
// lanes/node = HC/2; scalar logit folded pre-shuffle; reduce over C/2 lanes.
template<int H, int C>
__global__ __launch_bounds__(256) void k_edge(const bf16* __restrict__ XL, const bf16* __restrict__ XR,
                                              const float2* __restrict__ eaP, const int* __restrict__ off,
                                              const int* __restrict__ csr_src, const float* __restrict__ att,
                                              const float* __restrict__ We, const float* __restrict__ bias,
                                              bf16* __restrict__ Hout){
  const int HC = H*C;
  const int LPN = HC/2;            // lanes per node
  const int NPW = 64/LPN;          // nodes per wave
  const int NPB = 4*NPW;           // nodes per block (4 waves)
  int tid = threadIdx.x;
  int lane = tid & 63, wv = tid >> 6;
  int ln = lane % LPN;
  int n  = blockIdx.x*NPB + wv*NPW + lane/LPN;
  int g  = blockIdx.y;
  int c0 = 2*ln;
  size_t gbase = (size_t)g*NNODES*HC;
  const unsigned* XLu = (const unsigned*)(XL + gbase);
  unsigned xru = ((const unsigned*)(XR + gbase))[n*LPN + ln];
  float xr0 = __uint_as_float(xru<<16);
  float xr1 = __uint_as_float(xru & 0xffff0000u);
  float av0 = att[c0], av1 = att[c0+1];
  float w00 = We[c0], w01 = We[c0+1];
  float w10 = We[HC+c0], w11 = We[HC+c0+1];
  float srun = 0.f, acc0 = 0.f, acc1 = 0.f;
  int p0 = off[n], p1 = off[n+1];
  int p = p0;
  for (; p+2 <= p1; p += 2){
    int uA = csr_src[p], uB = csr_src[p+1];
    float2 eA = eaP[p], eB = eaP[p+1];
    unsigned xlA = XLu[uA*LPN + ln];
    unsigned xlB = XLu[uB*LPN + ln];
    float xa0 = __uint_as_float(xlA<<16), xa1 = __uint_as_float(xlA & 0xffff0000u);
    float xb0 = __uint_as_float(xlB<<16), xb1 = __uint_as_float(xlB & 0xffff0000u);
    float sa0 = xa0 + fmaf(eA.x,w00, fmaf(eA.y,w10, xr0));
    float sa1 = xa1 + fmaf(eA.x,w01, fmaf(eA.y,w11, xr1));
    float sb0 = xb0 + fmaf(eB.x,w00, fmaf(eB.y,w10, xr0));
    float sb1 = xb1 + fmaf(eB.x,w01, fmaf(eB.y,w11, xr1));
    float ma0 = sa0>0.f?sa0:0.2f*sa0, ma1 = sa1>0.f?sa1:0.2f*sa1;
    float mb0 = sb0>0.f?sb0:0.2f*sb0, mb1 = sb1>0.f?sb1:0.2f*sb1;
    float cA = fmaf(ma0,av0, ma1*av1);
    float cB = fmaf(mb0,av0, mb1*av1);
    #pragma unroll
    for (int d=C/4; d>=1; d>>=1){ cA += __shfl_xor(cA, d); cB += __shfl_xor(cB, d); }
    float peA = __expf(cA), peB = __expf(cB);
    srun += peA + peB;
    acc0 = fmaf(peA, xa0, fmaf(peB, xb0, acc0));
    acc1 = fmaf(peA, xa1, fmaf(peB, xb1, acc1));
  }
  if (p < p1){
    int uA = csr_src[p];
    float2 eA = eaP[p];
    unsigned xlA = XLu[uA*LPN + ln];
    float xa0 = __uint_as_float(xlA<<16), xa1 = __uint_as_float(xlA & 0xffff0000u);
    float sa0 = xa0 + fmaf(eA.x,w00, fmaf(eA.y,w10, xr0));
    float sa1 = xa1 + fmaf(eA.x,w01, fmaf(eA.y,w11, xr1));
    float ma0 = sa0>0.f?sa0:0.2f*sa0, ma1 = sa1>0.f?sa1:0.2f*sa1;
    float cA = fmaf(ma0,av0, ma1*av1);
    #pragma unroll
    for (int d=C/4; d>=1; d>>=1) cA += __shfl_xor(cA, d);
    float peA = __expf(cA);
    srun += peA;
    acc0 = fmaf(peA, xa0, acc0);
    acc1 = fmaf(peA, xa1, acc1);
  }
  float inv = 1.f/(srun + 1e-16f);
  float o0 = fmaf(acc0, inv, bias[c0]);
  float o1 = fmaf(acc1, inv, bias[c0+1]);
  o0 = o0>0.f?o0:0.f; o1 = o1>0.f?o1:0.f;
  unsigned r0 = (unsigned)(unsigned short)bfbits(o0);
  unsigned r1 = (unsigned)(unsigned short)bfbits(o1);
  ((unsigned*)(Hout + gbase))[n*LPN + ln] = (r1<<16) | r0;
}

// ---------- gates_x[bt][j] = emb[bt] . w_ih[j] via MFMA (w cvt to bf16 in-reg) ----------
#define GATES_KS 40
__global__ __launch_bounds__(256) void k_gates_mf(const bf16* __restrict__ emb, const float* __restrict__ wih,
                                                  float* __restrict__ gates){
  const int nk = 2000/GATES_KS;   // 50 k-steps of 32
  int lane = threadIdx.x & 63, wv = threadIdx.x >> 6;
  int r = lane & 15, kg = lane >> 4;
  int j0 = (blockIdx.x*4 + wv)*16;
  int k0 = blockIdx.y*nk*32;
  const f32x4 zero = {0.f,0.f,0.f,0.f};
  f32x4 acc0 = zero, acc1 = zero, acc2 = zero;
  const float* wrow = wih + (size_t)(j0 + r)*64000;
  const bf16*  e0p  = emb + (size_t)r*64000;
  const bf16*  e1p  = emb + (size_t)(16+r)*64000;
  const bf16*  e2p  = emb + (size_t)(32+r)*64000;  // rows 40-47 garbage-safe (C rows never written)
  #pragma unroll 2
  for (int s=0; s<nk; ++s){
    int k = k0 + s*32 + kg*8;
    float4 wa = *(const float4*)(wrow + k);
    float4 wb = *(const float4*)(wrow + k + 4);
    short8 bfr;
    bfr[0]=bfbits(wa.x); bfr[1]=bfbits(wa.y); bfr[2]=bfbits(wa.z); bfr[3]=bfbits(wa.w);
    bfr[4]=bfbits(wb.x); bfr[5]=bfbits(wb.y); bfr[6]=bfbits(wb.z); bfr[7]=bfbits(wb.w);
    short8 a0 = *(const short8*)(e0p + k);
    short8 a1 = *(const short8*)(e1p + k);
    short8 a2 = *(const short8*)(e2p + k);
    acc0 = __builtin_amdgcn_mfma_f32_16x16x32_bf16(a0, bfr, acc0, 0,0,0);
    acc1 = __builtin_amdgcn_mfma_f32_16x16x32_bf16(a1, bfr, acc1, 0,0,0);
    acc2 = __builtin_amdgcn_mfma_f32_16x16x32_bf16(a2, bfr, acc2, 0,0,0);
  }
  int col = j0 + r;
  #pragma unroll
  for (int i=0;i<4;i++){
    int row = kg*4 + i;
    atomicAdd(&gates[(size_t)row*1024 + col], acc0[i]);
    atomicAdd(&gates[(size_t)(row+16)*1024 + col], acc1[i]);
    if (row + 32 < 40) atomicAdd(&gates[(size_t)(row+32)*1024 + col], acc2[i]);
  }
}

// ---------- fused 10-step LSTM: 4 blocks (one per batch) ----------
__global__ __launch_bounds__(1024) void k_lstm10(const float* __restrict__ gates, const unsigned* __restrict__ whhT2,
                                                 const float* __restrict__ bih, const float* __restrict__ bhh,
                                                 float* __restrict__ hst){
  __shared__ float hs[256];
  __shared__ float g[1024];
  int b = blockIdx.x, j = threadIdx.x;
  float c_reg = 0.f;
  if (j < 256) hs[j] = 0.f;
  float bias = bih[j] + bhh[j];
  __syncthreads();
  for (int t=0;t<10;t++){
    float acc = gates[(size_t)(b*10+t)*1024 + j] + bias;
    #pragma unroll 16
    for (int kp=0;kp<128;kp++){
      unsigned u = whhT2[kp*1024 + j];
      float2 h2 = *(const float2*)&hs[2*kp];
      acc = fmaf(__uint_as_float(u<<16), h2.x, acc);
      acc = fmaf(__uint_as_float(u & 0xffff0000u), h2.y, acc);
    }
    g[j] = acc;
    __syncthreads();
    if (j < 256){
      float i_ = g[j], f_ = g[j+256], gg = g[j+512], o_ = g[j+768];
      float si = 1.f/(1.f+__expf(-i_));
      float sf = 1.f/(1.f+__expf(-f_));
      float so = 1.f/(1.f+__expf(-o_));
      c_reg = sf*c_reg + si*tanhf(gg);
      float hn = so*tanhf(c_reg);
      hs[j] = hn;
      if (t==9) hst[b*256+j] = hn;
    }
    __syncthreads();
  }
}

// ---------- head: relu(h) @ fc1 -> relu -> @ fc2 ----------
__global__ __launch_bounds__(512) void k_head(const float* __restrict__ hst, const float* __restrict__ fc1w,
                                              const float* __restrict__ fc1b, const float* __restrict__ fc2w,
                                              const float* __restrict__ fc2b, float* __restrict__ out){
  __shared__ float r[512];
  int b = blockIdx.x, j = threadIdx.x;
  float acc = fc1b[j];
  for (int k=0;k<256;k++){
    float l = hst[b*256+k]; l = l>0.f?l:0.f;
    acc += l * fc1w[k*512 + j];
  }
  float hid = acc>0.f?acc:0.f;
  r[j] = hid * fc2w[j];
  __syncthreads();
  for (int d=256; d>=1; d>>=1){ if (j<d) r[j]+=r[j+d]; __syncthreads(); }
  if (j==0) out[b] = r[0] + fc2b[0];
}

extern "C" void kernel_launch(void* const* d_in, const int* in_sizes, int n_in,
                              void* d_out, int out_size, void* d_ws, size_t ws_size,
                              hipStream_t stream){
  const float* x    = (const float*)d_in[0];
  const int*   ei   = (const int*)  d_in[1];
  const float* ea   = (const float*)d_in[2];
  const float* wl0  = (const float*)d_in[3];
  const float* wr0  = (const float*)d_in[4];
  const float* we0  = (const float*)d_in[5];
  const float* att0 = (const float*)d_in[6];
  const float* b0   = (const float*)d_in[7];
  const float* wl1  = (const float*)d_in[8];
  const float* wr1  = (const float*)d_in[9];
  const float* we1  = (const float*)d_in[10];
  const float* att1 = (const float*)d_in[11];
  const float* b1   = (const float*)d_in[12];
  const float* wl2  = (const float*)d_in[13];
  const float* wr2  = (const float*)d_in[14];
  const float* we2  = (const float*)d_in[15];
  const float* att2 = (const float*)d_in[16];
  const float* b2   = (const float*)d_in[17];
  const float* wih  = (const float*)d_in[18];
  const float* whh  = (const float*)d_in[19];
  const float* bih  = (const float*)d_in[20];
  const float* bhh  = (const float*)d_in[21];
  const float* fc1w = (const float*)d_in[22];
  const float* fc1b = (const float*)d_in[23];
  const float* fc2w = (const float*)d_in[24];
  const float* fc2b = (const float*)d_in[25];
  float* out = (float*)d_out;

  char* base = (char*)d_ws; size_t cur = 0;
  auto alloc = [&](size_t bytes)->void*{
    cur = (cur + 255) & ~(size_t)255; void* p = base + cur; cur += bytes; return p;
  };
  float* mean_ea = (float*)alloc(8);
  int*   cnt     = (int*)  alloc((size_t)NNODES*4);
  int*   off     = (int*)  alloc((size_t)(NNODES+1)*4);
  int*   cursor  = (int*)  alloc((size_t)NNODES*4);
  int*   csr_src = (int*)  alloc((size_t)NEDGE*4);
  float2* eaP    = (float2*)alloc((size_t)NEDGE*8);
  bf16*  XL      = (bf16*) alloc((size_t)80000*128*2);
  bf16*  XR      = (bf16*) alloc((size_t)80000*128*2);
  bf16*  HBUF    = (bf16*) alloc((size_t)80000*128*2);
  float* gates   = (float*)alloc((size_t)40*1024*4);
  float* hst     = (float*)alloc(4*256*4);
  unsigned* whhT2= (unsigned*)alloc((size_t)128*1024*4);
  bf16*  bt1a    = (bf16*) alloc((size_t)128*128*2);
  bf16*  bt1b    = (bf16*) alloc((size_t)128*128*2);
  bf16*  bt2a    = (bf16*) alloc((size_t)32*128*2);
  bf16*  bt2b    = (bf16*) alloc((size_t)32*128*2);

  // fused setup (mean_ea + whh pack + weight cvt + zeroing)
  k_setup <<<849,256,0,stream>>>(ea, mean_ea, whh, whhT2, wl1, wr1, wl2, wr2,
                                 bt1a, bt1b, bt2a, bt2b, cnt, cursor, gates);
  k_count   <<<(NEDGE+255)/256,256,0,stream>>>(ei, cnt);
  k_scan    <<<1,64,0,stream>>>(cnt, off);
  k_scatter <<<(NEDGE+255)/256,256,0,stream>>>(ei, off, cursor, ea, mean_ea, csr_src, eaP);

  // Layer 0 (Fin=8 -> H=4,C=32), fused Wl+Wr
  k_gemm0   <<<10000,256,0,stream>>>(x, wl0, wr0, XL, XR);
  k_edge<4,32> <<<dim3(500,40),256,0,stream>>>(XL,XR,eaP,off,csr_src,att0,we0,b0,HBUF);

  // Layer 1 (128 -> H=4,C=32), fused MFMA pair
  k_gemm_mf2<128> <<<625,256,0,stream>>>(HBUF, bt1a, bt1b, XL, XR);
  k_edge<4,32> <<<dim3(500,40),256,0,stream>>>(XL,XR,eaP,off,csr_src,att1,we1,b1,HBUF);

  // Layer 2 (128 -> H=4,C=8), fused MFMA pair; output emb bf16 [40][64000] in HBUF
  k_gemm_mf2<32> <<<625,256,0,stream>>>(HBUF, bt2a, bt2b, XL, XR);
  k_edge<4,8> <<<dim3(125,40),256,0,stream>>>(XL,XR,eaP,off,csr_src,att2,we2,b2,HBUF);

  // gates_x = emb @ w_ih^T via MFMA (in-register f32->bf16 of w_ih)
  k_gates_mf<<<dim3(16,GATES_KS),256,0,stream>>>(HBUF, wih, gates);

  // fused LSTM (10 steps in one launch)
  k_lstm10<<<4,1024,0,stream>>>(gates, whhT2, bih, bhh, hst);

  k_head<<<4,512,0,stream>>>(hst, fc1w, fc1b, fc2w, fc2b, out);
}